// Round 2
// baseline (721.277 us; speedup 1.0000x reference)
//
#include <hip/hip_runtime.h>
#include <stdint.h>

typedef uint16_t u16;
typedef __attribute__((ext_vector_type(8))) short bf16x8;
typedef __attribute__((ext_vector_type(4))) float f32x4;

__device__ inline u16 f2b(float f) {          // fp32 -> bf16 RNE
  uint32_t u = __float_as_uint(f);
  u += 0x7FFF + ((u >> 16) & 1);
  return (u16)(u >> 16);
}
__device__ inline float b2f(u16 h) {          // bf16 -> fp32 exact
  return __uint_as_float(((uint32_t)h) << 16);
}

// ---------------------------------------------------------------------------
// Dtype probe: if inputs are fp32 misdeclared as bf16, the low u16 of each
// fp32 word decodes to a wild bf16 (|v|>1000 or NaN) ~47% of the time.
// Genuine bf16 N(0,1) data never does. Writes mode (0=bf16, 1=fp32) to flag.
// ---------------------------------------------------------------------------
__global__ void k_detect(const u16* __restrict__ X, int* __restrict__ flag) {
  __shared__ int cnt;
  const int t = threadIdx.x;              // 256 threads, 1 block
  if (t == 0) cnt = 0;
  __syncthreads();
  float av = fabsf(b2f(X[t * 2]));        // even u16 = fp32 low half (if fp32)
  int wild = (av < 1000.0f) ? 0 : 1;      // NaN compares false -> wild=1
  atomicAdd(&cnt, wild);
  __syncthreads();
  if (t == 0) flag[0] = (cnt > 16) ? 1 : 0;
}

// ---------------------------------------------------------------------------
// Kernel 1: qkv = x @ w_qkv^T (bf16 MFMA NT, 64x64 tile), RoPE in epilogue.
// Each 64-wide n-tile is one (e,h). Writes q,k,v bf16 in (B,H,S,Dh).
// ---------------------------------------------------------------------------
__global__ __launch_bounds__(256) void k_qkv_rope(const void* __restrict__ Xv,
                                                  const void* __restrict__ Wv,
                                                  const int* __restrict__ flag,
                                                  u16* __restrict__ Qo,
                                                  u16* __restrict__ Ko,
                                                  u16* __restrict__ Vo) {
  __shared__ u16 As[64][40];
  __shared__ u16 Bs[64][40];
  __shared__ float Cs[64][66];
  const int mode = flag[0];
  const int n0 = blockIdx.x * 64, m0 = blockIdx.y * 64;
  const int t = threadIdx.x, w = t >> 6, lane = t & 63;
  const int lr = lane & 15, lq = lane >> 4;
  f32x4 acc[4] = {};
  const int rA = t >> 2, cA = (t & 3) * 8;
  const int aoff = (m0 + rA) * 1024 + cA;
  const int boff = (n0 + rA) * 1024 + cA;
  for (int k0 = 0; k0 < 1024; k0 += 32) {
    __syncthreads();
    if (mode == 0) {
      *(uint4*)&As[rA][cA] = *(const uint4*)((const u16*)Xv + aoff + k0);
      *(uint4*)&Bs[rA][cA] = *(const uint4*)((const u16*)Wv + boff + k0);
    } else {
      const float* Xf = (const float*)Xv;
      const float* Wf = (const float*)Wv;
#pragma unroll
      for (int e = 0; e < 8; ++e) {
        As[rA][cA + e] = f2b(Xf[aoff + k0 + e]);
        Bs[rA][cA + e] = f2b(Wf[boff + k0 + e]);
      }
    }
    __syncthreads();
    // B frag: lane holds B[n = w*16 + (lane&15)][k = (lane>>4)*8 + j]
    bf16x8 bf = *(const bf16x8*)&Bs[(w << 4) + lr][lq * 8];
#pragma unroll
    for (int mt = 0; mt < 4; ++mt) {
      // A frag: lane holds A[m = mt*16 + (lane&15)][k = (lane>>4)*8 + j]
      bf16x8 af = *(const bf16x8*)&As[(mt << 4) + lr][lq * 8];
      acc[mt] = __builtin_amdgcn_mfma_f32_16x16x32_bf16(af, bf, acc[mt], 0, 0, 0);
    }
  }
  // C/D layout (m89-verified): col = lane&15, row = (lane>>4)*4 + reg
  {
    const int col = (w << 4) + lr;
#pragma unroll
    for (int mt = 0; mt < 4; ++mt)
#pragma unroll
      for (int i = 0; i < 4; ++i)
        Cs[mt * 16 + lq * 4 + i][col] = acc[mt][i];
  }
  __syncthreads();
  const int e = n0 >> 10;          // 0=q 1=k 2=v
  const int h = (n0 >> 6) & 15;
  const int r = t >> 2, dh0 = (t & 3) * 16;
  const int m = m0 + r, b = m >> 11, s = m & 2047;
  const int obase = ((b * 16 + h) * 2048 + s) * 64;
  if (e == 2) {
#pragma unroll
    for (int u = 0; u < 16; ++u) Vo[obase + dh0 + u] = f2b(Cs[r][dh0 + u]);
  } else {
    u16* O = (e == 0) ? Qo : Ko;
#pragma unroll
    for (int u = 0; u < 16; ++u) {
      int dh = dh0 + u;
      float v  = Cs[r][dh];
      float vp = Cs[r][dh ^ 32];                 // rotate_half partner
      float sign = (dh < 32) ? -1.0f : 1.0f;
      float ang = (float)s * powf(10000.0f, -(float)(dh & 31) * (1.0f / 32.0f));
      float sn, cs;
      sincosf(ang, &sn, &cs);
      O[obase + dh] = f2b(v * cs + sign * vp * sn);
    }
  }
}

// ---------------------------------------------------------------------------
// Kernel 2: causal flash attention, fp32 VALU, 64x64 tiles, bf16 q/k/v in,
// bf16 ao out in (B,S,H*Dh). P-tile aliases Ks LDS.
// ---------------------------------------------------------------------------
__global__ __launch_bounds__(256) void k_attn(const u16* __restrict__ Q,
                                              const u16* __restrict__ K,
                                              const u16* __restrict__ V,
                                              u16* __restrict__ AO) {
  __shared__ float Qs[64][68];
  __shared__ float Ks[64][68];   // reused as P-tile after scores are read
  __shared__ float Vs[64][68];
  const int qt = blockIdx.x;     // q tile 0..31
  const int bh = blockIdx.y;     // b*16+h
  const int b = bh >> 4, h = bh & 15;
  const u16* Qg = Q + (bh * 2048 + qt * 64) * 64;
  const u16* Kg = K + bh * 2048 * 64;
  const u16* Vg = V + bh * 2048 * 64;
  const int t = threadIdx.x;
  const int tx = t & 15, ty = t >> 4;
#pragma unroll
  for (int g = 0; g < 2; ++g) {
    int f = t * 2 + g, r = f >> 3, c = (f & 7) * 8;
    union { uint4 u; u16 hx[8]; } raw;
    raw.u = *(const uint4*)&Qg[r * 64 + c];
#pragma unroll
    for (int e2 = 0; e2 < 8; ++e2) Qs[r][c + e2] = b2f(raw.hx[e2]);
  }
  float m_i[4], l_i[4], o[4][4];
#pragma unroll
  for (int i = 0; i < 4; ++i) {
    m_i[i] = -3.0e4f; l_i[i] = 0.f;
#pragma unroll
    for (int j = 0; j < 4; ++j) o[i][j] = 0.f;
  }
  for (int kt = 0; kt <= qt; ++kt) {
    __syncthreads();
#pragma unroll
    for (int g = 0; g < 2; ++g) {
      int f = t * 2 + g, r = f >> 3, c = (f & 7) * 8;
      union { uint4 u; u16 hx[8]; } rk, rv;
      rk.u = *(const uint4*)&Kg[kt * 4096 + r * 64 + c];
      rv.u = *(const uint4*)&Vg[kt * 4096 + r * 64 + c];
#pragma unroll
      for (int e2 = 0; e2 < 8; ++e2) {
        Ks[r][c + e2] = b2f(rk.hx[e2]);
        Vs[r][c + e2] = b2f(rv.hx[e2]);
      }
    }
    __syncthreads();
    // scores: rows ty*4+i, cols tx + 16*j
    float sc[4][4] = {};
    for (int kk = 0; kk < 64; kk += 4) {
      float4 qv[4], kv[4];
#pragma unroll
      for (int i = 0; i < 4; ++i) qv[i] = *(const float4*)&Qs[ty * 4 + i][kk];
#pragma unroll
      for (int j = 0; j < 4; ++j) kv[j] = *(const float4*)&Ks[tx + 16 * j][kk];
#pragma unroll
      for (int i = 0; i < 4; ++i)
#pragma unroll
        for (int j = 0; j < 4; ++j)
          sc[i][j] += qv[i].x * kv[j].x + qv[i].y * kv[j].y +
                      qv[i].z * kv[j].z + qv[i].w * kv[j].w;
    }
#pragma unroll
    for (int i = 0; i < 4; ++i)
#pragma unroll
      for (int j = 0; j < 4; ++j) {
        float sv = sc[i][j] * 0.125f;                              // Dh^-0.5
        if (kt == qt && (tx + 16 * j) > (ty * 4 + i)) sv = -3.0e4f; // causal
        sc[i][j] = sv;
      }
    float alpha[4];
#pragma unroll
    for (int i = 0; i < 4; ++i) {
      float mx = fmaxf(fmaxf(sc[i][0], sc[i][1]), fmaxf(sc[i][2], sc[i][3]));
      mx = fmaxf(mx, __shfl_xor(mx, 1));
      mx = fmaxf(mx, __shfl_xor(mx, 2));
      mx = fmaxf(mx, __shfl_xor(mx, 4));
      mx = fmaxf(mx, __shfl_xor(mx, 8));
      float mnew = fmaxf(m_i[i], mx);
      alpha[i] = __expf(m_i[i] - mnew);
      float sm = 0.f;
#pragma unroll
      for (int j = 0; j < 4; ++j) { sc[i][j] = __expf(sc[i][j] - mnew); sm += sc[i][j]; }
      sm += __shfl_xor(sm, 1); sm += __shfl_xor(sm, 2);
      sm += __shfl_xor(sm, 4); sm += __shfl_xor(sm, 8);
      l_i[i] = l_i[i] * alpha[i] + sm;
      m_i[i] = mnew;
#pragma unroll
      for (int j = 0; j < 4; ++j) o[i][j] *= alpha[i];
    }
    __syncthreads();           // all Ks reads done -> safe to overwrite as P
#pragma unroll
    for (int i = 0; i < 4; ++i)
#pragma unroll
      for (int j = 0; j < 4; ++j)
        Ks[ty * 4 + i][tx + 16 * j] = sc[i][j];
    __syncthreads();
    for (int c = 0; c < 64; ++c) {
      float4 vv = *(const float4*)&Vs[c][tx * 4];
#pragma unroll
      for (int i = 0; i < 4; ++i) {
        float pv = Ks[ty * 4 + i][c];
        o[i][0] += pv * vv.x; o[i][1] += pv * vv.y;
        o[i][2] += pv * vv.z; o[i][3] += pv * vv.w;
      }
    }
  }
#pragma unroll
  for (int i = 0; i < 4; ++i) {
    float inv = 1.0f / l_i[i];
    int row = qt * 64 + ty * 4 + i;
    int ob = (b * 2048 + row) * 1024 + h * 64 + tx * 4;
#pragma unroll
    for (int j = 0; j < 4; ++j) AO[ob + j] = f2b(o[i][j] * inv);
  }
}

// ---------------------------------------------------------------------------
// Kernel 3: out = ao @ w_out^T (bf16 MFMA NT). Output dtype per mode flag.
// ---------------------------------------------------------------------------
__global__ __launch_bounds__(256) void k_gemm_out(const u16* __restrict__ A,
                                                  const void* __restrict__ Bv,
                                                  const int* __restrict__ flag,
                                                  void* __restrict__ Cv) {
  __shared__ u16 As[64][40];
  __shared__ u16 Bs[64][40];
  const int mode = flag[0];
  const int n0 = blockIdx.x * 64, m0 = blockIdx.y * 64;
  const int t = threadIdx.x, w = t >> 6, lane = t & 63;
  const int lr = lane & 15, lq = lane >> 4;
  f32x4 acc[4] = {};
  const int rA = t >> 2, cA = (t & 3) * 8;
  const int aoff = (m0 + rA) * 1024 + cA;
  const int boff = (n0 + rA) * 1024 + cA;
  for (int k0 = 0; k0 < 1024; k0 += 32) {
    __syncthreads();
    *(uint4*)&As[rA][cA] = *(const uint4*)(A + aoff + k0);
    if (mode == 0) {
      *(uint4*)&Bs[rA][cA] = *(const uint4*)((const u16*)Bv + boff + k0);
    } else {
      const float* Bf = (const float*)Bv;
#pragma unroll
      for (int e = 0; e < 8; ++e) Bs[rA][cA + e] = f2b(Bf[boff + k0 + e]);
    }
    __syncthreads();
    bf16x8 bf = *(const bf16x8*)&Bs[(w << 4) + lr][lq * 8];
#pragma unroll
    for (int mt = 0; mt < 4; ++mt) {
      bf16x8 af = *(const bf16x8*)&As[(mt << 4) + lr][lq * 8];
      acc[mt] = __builtin_amdgcn_mfma_f32_16x16x32_bf16(af, bf, acc[mt], 0, 0, 0);
    }
  }
  const int col = n0 + (w << 4) + lr;
  if (mode == 0) {
    u16* C = (u16*)Cv;
#pragma unroll
    for (int mt = 0; mt < 4; ++mt)
#pragma unroll
      for (int i = 0; i < 4; ++i)
        C[(m0 + mt * 16 + lq * 4 + i) * 1024 + col] = f2b(acc[mt][i]);
  } else {
    float* C = (float*)Cv;
#pragma unroll
    for (int mt = 0; mt < 4; ++mt)
#pragma unroll
      for (int i = 0; i < 4; ++i)
        C[(m0 + mt * 16 + lq * 4 + i) * 1024 + col] = acc[mt][i];
  }
}

// ---------------------------------------------------------------------------
extern "C" void kernel_launch(void* const* d_in, const int* in_sizes, int n_in,
                              void* d_out, int out_size, void* d_ws, size_t ws_size,
                              hipStream_t stream) {
  const void* x    = d_in[0];   // (4096,1024)  bf16 or fp32
  const void* wqkv = d_in[1];   // (3072,1024)
  const void* wout = d_in[2];   // (1024,1024)

  // ws layout: [flag 256B][q 8.39MB][k][v][ao]  -> 33.6 MB total (bf16)
  int* flag = (int*)d_ws;
  u16* qb = (u16*)((char*)d_ws + 256);
  u16* kb = qb + 4194304;
  u16* vb = kb + 4194304;
  u16* ao = vb + 4194304;

  k_detect  <<<dim3(1), 256, 0, stream>>>((const u16*)x, flag);
  k_qkv_rope<<<dim3(48, 64), 256, 0, stream>>>(x, wqkv, flag, qb, kb, vb);
  k_attn    <<<dim3(32, 32), 256, 0, stream>>>(qb, kb, vb, ao);
  k_gemm_out<<<dim3(16, 64), 256, 0, stream>>>(ao, wout, flag, d_out);
}

// Round 3
// 343.272 us; speedup vs baseline: 2.1012x; 2.1012x over previous
//
#include <hip/hip_runtime.h>
#include <stdint.h>

typedef uint16_t u16;
typedef __attribute__((ext_vector_type(8))) short bf16x8;
typedef __attribute__((ext_vector_type(4))) float f32x4;

__device__ inline u16 f2b(float f) {          // fp32 -> bf16 RNE
  uint32_t u = __float_as_uint(f);
  u += 0x7FFF + ((u >> 16) & 1);
  return (u16)(u >> 16);
}
__device__ inline float b2f(u16 h) {          // bf16 -> fp32 exact
  return __uint_as_float(((uint32_t)h) << 16);
}

// ---------------------------------------------------------------------------
// Dtype probe (kept from R1): mode 0 = bf16 inputs (confirmed), 1 = fp32.
// ---------------------------------------------------------------------------
__global__ void k_detect(const u16* __restrict__ X, int* __restrict__ flag) {
  __shared__ int cnt;
  const int t = threadIdx.x;
  if (t == 0) cnt = 0;
  __syncthreads();
  float av = fabsf(b2f(X[t * 2]));
  int wild = (av < 1000.0f) ? 0 : 1;
  atomicAdd(&cnt, wild);
  __syncthreads();
  if (t == 0) flag[0] = (cnt > 16) ? 1 : 0;
}

// ---------------------------------------------------------------------------
// Kernel 1: qkv = x @ w_qkv^T (bf16 MFMA NT, 64x64 tile), RoPE in epilogue.
// Q,K written bf16 (B,H,S,Dh); V written TRANSPOSED bf16 (B,H,Dh,S) so the
// attention kernel's PV B-fragment is a natural contiguous row read.
// ---------------------------------------------------------------------------
__global__ __launch_bounds__(256) void k_qkv_rope(const void* __restrict__ Xv,
                                                  const void* __restrict__ Wv,
                                                  const int* __restrict__ flag,
                                                  u16* __restrict__ Qo,
                                                  u16* __restrict__ Ko,
                                                  u16* __restrict__ Vo) {
  __shared__ u16 As[64][40];
  __shared__ u16 Bs[64][40];
  __shared__ float Cs[64][66];
  const int mode = flag[0];
  const int n0 = blockIdx.x * 64, m0 = blockIdx.y * 64;
  const int t = threadIdx.x, w = t >> 6, lane = t & 63;
  const int lr = lane & 15, lq = lane >> 4;
  f32x4 acc[4] = {};
  const int rA = t >> 2, cA = (t & 3) * 8;
  const int aoff = (m0 + rA) * 1024 + cA;
  const int boff = (n0 + rA) * 1024 + cA;
  for (int k0 = 0; k0 < 1024; k0 += 32) {
    __syncthreads();
    if (mode == 0) {
      *(uint4*)&As[rA][cA] = *(const uint4*)((const u16*)Xv + aoff + k0);
      *(uint4*)&Bs[rA][cA] = *(const uint4*)((const u16*)Wv + boff + k0);
    } else {
      const float* Xf = (const float*)Xv;
      const float* Wf = (const float*)Wv;
#pragma unroll
      for (int e = 0; e < 8; ++e) {
        As[rA][cA + e] = f2b(Xf[aoff + k0 + e]);
        Bs[rA][cA + e] = f2b(Wf[boff + k0 + e]);
      }
    }
    __syncthreads();
    bf16x8 bf = *(const bf16x8*)&Bs[(w << 4) + lr][lq * 8];
#pragma unroll
    for (int mt = 0; mt < 4; ++mt) {
      bf16x8 af = *(const bf16x8*)&As[(mt << 4) + lr][lq * 8];
      acc[mt] = __builtin_amdgcn_mfma_f32_16x16x32_bf16(af, bf, acc[mt], 0, 0, 0);
    }
  }
  {
    const int col = (w << 4) + lr;
#pragma unroll
    for (int mt = 0; mt < 4; ++mt)
#pragma unroll
      for (int i = 0; i < 4; ++i)
        Cs[mt * 16 + lq * 4 + i][col] = acc[mt][i];
  }
  __syncthreads();
  const int e = n0 >> 10;          // 0=q 1=k 2=v
  const int h = (n0 >> 6) & 15;
  if (e == 2) {
    // transposed V write: Vo[((b*16+h)*64 + dh)*2048 + s]
    const int sx = t & 63, dh0 = (t >> 6) * 16;
    const int m = m0 + sx, b = m >> 11, s = m & 2047;
    const long hb = (long)(b * 16 + h) * 64;
#pragma unroll
    for (int u = 0; u < 16; ++u) {
      int dh = dh0 + u;
      Vo[(hb + dh) * 2048 + s] = f2b(Cs[sx][dh]);
    }
  } else {
    const int r = t >> 2, dh0 = (t & 3) * 16;
    const int m = m0 + r, b = m >> 11, s = m & 2047;
    const int obase = ((b * 16 + h) * 2048 + s) * 64;
    u16* O = (e == 0) ? Qo : Ko;
#pragma unroll
    for (int u = 0; u < 16; ++u) {
      int dh = dh0 + u;
      float v  = Cs[r][dh];
      float vp = Cs[r][dh ^ 32];
      float sign = (dh < 32) ? -1.0f : 1.0f;
      float ang = (float)s * powf(10000.0f, -(float)(dh & 31) * (1.0f / 32.0f));
      float sn, cs;
      sincosf(ang, &sn, &cs);
      O[obase + dh] = f2b(v * cs + sign * vp * sn);
    }
  }
}

// ---------------------------------------------------------------------------
// Kernel 2: causal flash attention, bf16 MFMA.
// Block = (b,h, 64-row q-tile); wave w owns q-rows [16w,16w+16) x all 64 cols
// -> softmax stats reduce entirely in-wave (shfl over lr lanes).
// K LDS (s,dh); V LDS comes pre-transposed (dh,s) from k_qkv_rope.
// P round-trips through the aliased Q LDS buffer in A-frag layout.
// ---------------------------------------------------------------------------
__global__ __launch_bounds__(256) void k_attn(const u16* __restrict__ Q,
                                              const u16* __restrict__ K,
                                              const u16* __restrict__ V,
                                              u16* __restrict__ AO) {
  __shared__ u16 QP[64][72];   // Q tile, later reused as P tile (A-frag layout)
  __shared__ u16 Ks[64][72];   // K tile: rows = key pos, cols = dh
  __shared__ u16 Vt[64][72];   // V tile transposed: rows = dh, cols = key pos
  const int qt = 31 - blockIdx.x;   // heavy tiles dispatch first
  const int bh = blockIdx.y;
  const int b = bh >> 4, h = bh & 15;
  const u16* Qg = Q + (bh * 2048 + qt * 64) * 64;
  const u16* Kg = K + bh * 2048 * 64;
  const u16* Vg = V + (long)bh * 64 * 2048;   // (dh, s) layout
  const int t = threadIdx.x, w = t >> 6, lane = t & 63;
  const int lr = lane & 15, lq = lane >> 4;
  const int r0 = t >> 3, c0 = (t & 7) * 8;

  // stage Q
  *(uint4*)&QP[r0][c0]      = *(const uint4*)&Qg[r0 * 64 + c0];
  *(uint4*)&QP[r0 + 32][c0] = *(const uint4*)&Qg[(r0 + 32) * 64 + c0];
  __syncthreads();
  bf16x8 qf[2];
#pragma unroll
  for (int kk = 0; kk < 2; ++kk)
    qf[kk] = *(const bf16x8*)&QP[w * 16 + lr][kk * 32 + lq * 8];

  float m_i[4], l_i[4];
  f32x4 o_acc[4] = {};
#pragma unroll
  for (int i = 0; i < 4; ++i) { m_i[i] = -3.0e4f; l_i[i] = 0.f; }

  for (int kt = 0; kt <= qt; ++kt) {
    __syncthreads();   // prev PV frag reads + qf reads done
    *(uint4*)&Ks[r0][c0]      = *(const uint4*)&Kg[(kt * 64 + r0) * 64 + c0];
    *(uint4*)&Ks[r0 + 32][c0] = *(const uint4*)&Kg[(kt * 64 + r0 + 32) * 64 + c0];
    *(uint4*)&Vt[r0][c0]      = *(const uint4*)&Vg[r0 * 2048 + kt * 64 + c0];
    *(uint4*)&Vt[r0 + 32][c0] = *(const uint4*)&Vg[(r0 + 32) * 2048 + kt * 64 + c0];
    __syncthreads();

    // S = Q K^T : wave w rows [16w,16w+16), cols nb*16+lr
    f32x4 sa[4] = {};
#pragma unroll
    for (int nb = 0; nb < 4; ++nb)
#pragma unroll
      for (int kk = 0; kk < 2; ++kk) {
        bf16x8 kf = *(const bf16x8*)&Ks[nb * 16 + lr][kk * 32 + lq * 8];
        sa[nb] = __builtin_amdgcn_mfma_f32_16x16x32_bf16(qf[kk], kf, sa[nb], 0, 0, 0);
      }

    // online softmax, all in-wave. lane's rows: w*16 + lq*4 + i
    float p[4][4];   // [nb][i]
#pragma unroll
    for (int i = 0; i < 4; ++i) {
      const int row = w * 16 + lq * 4 + i;
      float s0 = sa[0][i] * 0.125f, s1 = sa[1][i] * 0.125f;
      float s2 = sa[2][i] * 0.125f, s3 = sa[3][i] * 0.125f;
      if (kt == qt) {   // causal: col = nb*16+lr
        if (0 * 16 + lr > row) s0 = -3.0e4f;
        if (1 * 16 + lr > row) s1 = -3.0e4f;
        if (2 * 16 + lr > row) s2 = -3.0e4f;
        if (3 * 16 + lr > row) s3 = -3.0e4f;
      }
      float mx = fmaxf(fmaxf(s0, s1), fmaxf(s2, s3));
      mx = fmaxf(mx, __shfl_xor(mx, 1));
      mx = fmaxf(mx, __shfl_xor(mx, 2));
      mx = fmaxf(mx, __shfl_xor(mx, 4));
      mx = fmaxf(mx, __shfl_xor(mx, 8));
      float mnew = fmaxf(m_i[i], mx);
      float alpha = __expf(m_i[i] - mnew);
      p[0][i] = __expf(s0 - mnew); p[1][i] = __expf(s1 - mnew);
      p[2][i] = __expf(s2 - mnew); p[3][i] = __expf(s3 - mnew);
      float sm = p[0][i] + p[1][i] + p[2][i] + p[3][i];
      sm += __shfl_xor(sm, 1); sm += __shfl_xor(sm, 2);
      sm += __shfl_xor(sm, 4); sm += __shfl_xor(sm, 8);
      l_i[i] = l_i[i] * alpha + sm;
      m_i[i] = mnew;
      o_acc[0][i] *= alpha; o_acc[1][i] *= alpha;
      o_acc[2][i] *= alpha; o_acc[3][i] *= alpha;
    }
    // P -> LDS in A-frag layout (wave-private 16-row block of QP)
#pragma unroll
    for (int nb = 0; nb < 4; ++nb)
#pragma unroll
      for (int i = 0; i < 4; ++i)
        QP[w * 16 + lq * 4 + i][nb * 16 + lr] = f2b(p[nb][i]);
    __syncthreads();

    // O += P V : A = P rows, B = Vt rows (dh), acc cols nb*16+lr = dh
#pragma unroll
    for (int kk = 0; kk < 2; ++kk) {
      bf16x8 pf = *(const bf16x8*)&QP[w * 16 + lr][kk * 32 + lq * 8];
#pragma unroll
      for (int nb = 0; nb < 4; ++nb) {
        bf16x8 vf = *(const bf16x8*)&Vt[nb * 16 + lr][kk * 32 + lq * 8];
        o_acc[nb] = __builtin_amdgcn_mfma_f32_16x16x32_bf16(pf, vf, o_acc[nb], 0, 0, 0);
      }
    }
  }
  // epilogue: rows w*16+lq*4+i, dh col nb*16+lr; AO is (B,S,H*Dh)
#pragma unroll
  for (int i = 0; i < 4; ++i) {
    float inv = 1.0f / l_i[i];
    int row = qt * 64 + w * 16 + lq * 4 + i;
    int ob = (b * 2048 + row) * 1024 + h * 64;
#pragma unroll
    for (int nb = 0; nb < 4; ++nb)
      AO[ob + nb * 16 + lr] = f2b(o_acc[nb][i] * inv);
  }
}

// ---------------------------------------------------------------------------
// Kernel 3: out = ao @ w_out^T (bf16 MFMA NT). Output dtype per mode flag.
// ---------------------------------------------------------------------------
__global__ __launch_bounds__(256) void k_gemm_out(const u16* __restrict__ A,
                                                  const void* __restrict__ Bv,
                                                  const int* __restrict__ flag,
                                                  void* __restrict__ Cv) {
  __shared__ u16 As[64][40];
  __shared__ u16 Bs[64][40];
  const int mode = flag[0];
  const int n0 = blockIdx.x * 64, m0 = blockIdx.y * 64;
  const int t = threadIdx.x, w = t >> 6, lane = t & 63;
  const int lr = lane & 15, lq = lane >> 4;
  f32x4 acc[4] = {};
  const int rA = t >> 2, cA = (t & 3) * 8;
  const int aoff = (m0 + rA) * 1024 + cA;
  const int boff = (n0 + rA) * 1024 + cA;
  for (int k0 = 0; k0 < 1024; k0 += 32) {
    __syncthreads();
    *(uint4*)&As[rA][cA] = *(const uint4*)(A + aoff + k0);
    if (mode == 0) {
      *(uint4*)&Bs[rA][cA] = *(const uint4*)((const u16*)Bv + boff + k0);
    } else {
      const float* Bf = (const float*)Bv;
#pragma unroll
      for (int e = 0; e < 8; ++e) Bs[rA][cA + e] = f2b(Bf[boff + k0 + e]);
    }
    __syncthreads();
    bf16x8 bf = *(const bf16x8*)&Bs[(w << 4) + lr][lq * 8];
#pragma unroll
    for (int mt = 0; mt < 4; ++mt) {
      bf16x8 af = *(const bf16x8*)&As[(mt << 4) + lr][lq * 8];
      acc[mt] = __builtin_amdgcn_mfma_f32_16x16x32_bf16(af, bf, acc[mt], 0, 0, 0);
    }
  }
  const int col = n0 + (w << 4) + lr;
  if (mode == 0) {
    u16* C = (u16*)Cv;
#pragma unroll
    for (int mt = 0; mt < 4; ++mt)
#pragma unroll
      for (int i = 0; i < 4; ++i)
        C[(m0 + mt * 16 + lq * 4 + i) * 1024 + col] = f2b(acc[mt][i]);
  } else {
    float* C = (float*)Cv;
#pragma unroll
    for (int mt = 0; mt < 4; ++mt)
#pragma unroll
      for (int i = 0; i < 4; ++i)
        C[(m0 + mt * 16 + lq * 4 + i) * 1024 + col] = acc[mt][i];
  }
}

// ---------------------------------------------------------------------------
extern "C" void kernel_launch(void* const* d_in, const int* in_sizes, int n_in,
                              void* d_out, int out_size, void* d_ws, size_t ws_size,
                              hipStream_t stream) {
  const void* x    = d_in[0];   // (4096,1024)
  const void* wqkv = d_in[1];   // (3072,1024)
  const void* wout = d_in[2];   // (1024,1024)

  // ws: [flag 256B][q 8.39MB][k 8.39MB][v^T 8.39MB][ao 8.39MB] = 33.6 MB
  int* flag = (int*)d_ws;
  u16* qb = (u16*)((char*)d_ws + 256);
  u16* kb = qb + 4194304;
  u16* vb = kb + 4194304;
  u16* ao = vb + 4194304;

  k_detect  <<<dim3(1), 256, 0, stream>>>((const u16*)x, flag);
  k_qkv_rope<<<dim3(48, 64), 256, 0, stream>>>(x, wqkv, flag, qb, kb, vb);
  k_attn    <<<dim3(32, 32), 256, 0, stream>>>(qb, kb, vb, ao);
  k_gemm_out<<<dim3(16, 64), 256, 0, stream>>>(ao, wout, flag, d_out);
}

// Round 8
// 315.333 us; speedup vs baseline: 2.2874x; 1.0886x over previous
//
#include <hip/hip_runtime.h>
#include <stdint.h>

typedef uint16_t u16;
typedef __attribute__((ext_vector_type(8))) short bf16x8;
typedef __attribute__((ext_vector_type(4))) float f32x4;

__device__ inline u16 f2b(float f) {          // fp32 -> bf16 RNE
  uint32_t u = __float_as_uint(f);
  u += 0x7FFF + ((u >> 16) & 1);
  return (u16)(u >> 16);
}
__device__ inline float b2f(u16 h) {          // bf16 -> fp32 exact
  return __uint_as_float(((uint32_t)h) << 16);
}

// ---------------------------------------------------------------------------
// Dtype probe (R3-verbatim): mode 0 = bf16 inputs, 1 = fp32.
// ---------------------------------------------------------------------------
__global__ void k_detect(const u16* __restrict__ X, int* __restrict__ flag) {
  __shared__ int cnt;
  const int t = threadIdx.x;
  if (t == 0) cnt = 0;
  __syncthreads();
  float av = fabsf(b2f(X[t * 2]));
  int wild = (av < 1000.0f) ? 0 : 1;
  atomicAdd(&cnt, wild);
  __syncthreads();
  if (t == 0) flag[0] = (cnt > 16) ? 1 : 0;
}

// ---------------------------------------------------------------------------
// Kernel 1: qkv = x @ w_qkv^T (bf16 MFMA NT, 64x64 tile), RoPE in epilogue.
// R3-verbatim EXCEPT: powf+sincosf replaced by __expf/__sinf/__cosf
// (pure per-lane VALU change; no memory/layout/sync delta).
// ---------------------------------------------------------------------------
__global__ __launch_bounds__(256) void k_qkv_rope(const void* __restrict__ Xv,
                                                  const void* __restrict__ Wv,
                                                  const int* __restrict__ flag,
                                                  u16* __restrict__ Qo,
                                                  u16* __restrict__ Ko,
                                                  u16* __restrict__ Vo) {
  __shared__ u16 As[64][40];
  __shared__ u16 Bs[64][40];
  __shared__ float Cs[64][66];
  const int mode = flag[0];
  const int n0 = blockIdx.x * 64, m0 = blockIdx.y * 64;
  const int t = threadIdx.x, w = t >> 6, lane = t & 63;
  const int lr = lane & 15, lq = lane >> 4;
  f32x4 acc[4] = {};
  const int rA = t >> 2, cA = (t & 3) * 8;
  const int aoff = (m0 + rA) * 1024 + cA;
  const int boff = (n0 + rA) * 1024 + cA;
  for (int k0 = 0; k0 < 1024; k0 += 32) {
    __syncthreads();
    if (mode == 0) {
      *(uint4*)&As[rA][cA] = *(const uint4*)((const u16*)Xv + aoff + k0);
      *(uint4*)&Bs[rA][cA] = *(const uint4*)((const u16*)Wv + boff + k0);
    } else {
      const float* Xf = (const float*)Xv;
      const float* Wf = (const float*)Wv;
#pragma unroll
      for (int e = 0; e < 8; ++e) {
        As[rA][cA + e] = f2b(Xf[aoff + k0 + e]);
        Bs[rA][cA + e] = f2b(Wf[boff + k0 + e]);
      }
    }
    __syncthreads();
    bf16x8 bf = *(const bf16x8*)&Bs[(w << 4) + lr][lq * 8];
#pragma unroll
    for (int mt = 0; mt < 4; ++mt) {
      bf16x8 af = *(const bf16x8*)&As[(mt << 4) + lr][lq * 8];
      acc[mt] = __builtin_amdgcn_mfma_f32_16x16x32_bf16(af, bf, acc[mt], 0, 0, 0);
    }
  }
  {
    const int col = (w << 4) + lr;
#pragma unroll
    for (int mt = 0; mt < 4; ++mt)
#pragma unroll
      for (int i = 0; i < 4; ++i)
        Cs[mt * 16 + lq * 4 + i][col] = acc[mt][i];
  }
  __syncthreads();
  const int e = n0 >> 10;          // 0=q 1=k 2=v
  const int h = (n0 >> 6) & 15;
  if (e == 2) {
    // transposed V write: Vo[((b*16+h)*64 + dh)*2048 + s]
    const int sx = t & 63, dh0 = (t >> 6) * 16;
    const int m = m0 + sx, b = m >> 11, s = m & 2047;
    const long hb = (long)(b * 16 + h) * 64;
#pragma unroll
    for (int u = 0; u < 16; ++u) {
      int dh = dh0 + u;
      Vo[(hb + dh) * 2048 + s] = f2b(Cs[sx][dh]);
    }
  } else {
    const int r = t >> 2, dh0 = (t & 3) * 16;
    const int m = m0 + r, b = m >> 11, s = m & 2047;
    const int obase = ((b * 16 + h) * 2048 + s) * 64;
    u16* O = (e == 0) ? Qo : Ko;
#pragma unroll
    for (int u = 0; u < 16; ++u) {
      int dh = dh0 + u;
      float v  = Cs[r][dh];
      float vp = Cs[r][dh ^ 32];
      float sign = (dh < 32) ? -1.0f : 1.0f;
      // inv_freq = 10000^(-(dh&31)/32) = exp(-(dh&31) * ln(10000)/32)
      float fr  = __expf((float)(dh & 31) * -0.28782314f);
      float ang = (float)s * fr;
      float sn = __sinf(ang), cs = __cosf(ang);
      O[obase + dh] = f2b(v * cs + sign * vp * sn);
    }
  }
}

// ---------------------------------------------------------------------------
// Kernel 2: causal flash attention, bf16 MFMA (R3-verbatim).
// ---------------------------------------------------------------------------
__global__ __launch_bounds__(256) void k_attn(const u16* __restrict__ Q,
                                              const u16* __restrict__ K,
                                              const u16* __restrict__ V,
                                              u16* __restrict__ AO) {
  __shared__ u16 QP[64][72];
  __shared__ u16 Ks[64][72];
  __shared__ u16 Vt[64][72];
  const int qt = 31 - blockIdx.x;
  const int bh = blockIdx.y;
  const int b = bh >> 4, h = bh & 15;
  const u16* Qg = Q + (bh * 2048 + qt * 64) * 64;
  const u16* Kg = K + bh * 2048 * 64;
  const u16* Vg = V + (long)bh * 64 * 2048;
  const int t = threadIdx.x, w = t >> 6, lane = t & 63;
  const int lr = lane & 15, lq = lane >> 4;
  const int r0 = t >> 3, c0 = (t & 7) * 8;

  *(uint4*)&QP[r0][c0]      = *(const uint4*)&Qg[r0 * 64 + c0];
  *(uint4*)&QP[r0 + 32][c0] = *(const uint4*)&Qg[(r0 + 32) * 64 + c0];
  __syncthreads();
  bf16x8 qf[2];
#pragma unroll
  for (int kk = 0; kk < 2; ++kk)
    qf[kk] = *(const bf16x8*)&QP[w * 16 + lr][kk * 32 + lq * 8];

  float m_i[4], l_i[4];
  f32x4 o_acc[4] = {};
#pragma unroll
  for (int i = 0; i < 4; ++i) { m_i[i] = -3.0e4f; l_i[i] = 0.f; }

  for (int kt = 0; kt <= qt; ++kt) {
    __syncthreads();
    *(uint4*)&Ks[r0][c0]      = *(const uint4*)&Kg[(kt * 64 + r0) * 64 + c0];
    *(uint4*)&Ks[r0 + 32][c0] = *(const uint4*)&Kg[(kt * 64 + r0 + 32) * 64 + c0];
    *(uint4*)&Vt[r0][c0]      = *(const uint4*)&Vg[r0 * 2048 + kt * 64 + c0];
    *(uint4*)&Vt[r0 + 32][c0] = *(const uint4*)&Vg[(r0 + 32) * 2048 + kt * 64 + c0];
    __syncthreads();

    f32x4 sa[4] = {};
#pragma unroll
    for (int nb = 0; nb < 4; ++nb)
#pragma unroll
      for (int kk = 0; kk < 2; ++kk) {
        bf16x8 kf = *(const bf16x8*)&Ks[nb * 16 + lr][kk * 32 + lq * 8];
        sa[nb] = __builtin_amdgcn_mfma_f32_16x16x32_bf16(qf[kk], kf, sa[nb], 0, 0, 0);
      }

    float p[4][4];
#pragma unroll
    for (int i = 0; i < 4; ++i) {
      const int row = w * 16 + lq * 4 + i;
      float s0 = sa[0][i] * 0.125f, s1 = sa[1][i] * 0.125f;
      float s2 = sa[2][i] * 0.125f, s3 = sa[3][i] * 0.125f;
      if (kt == qt) {
        if (0 * 16 + lr > row) s0 = -3.0e4f;
        if (1 * 16 + lr > row) s1 = -3.0e4f;
        if (2 * 16 + lr > row) s2 = -3.0e4f;
        if (3 * 16 + lr > row) s3 = -3.0e4f;
      }
      float mx = fmaxf(fmaxf(s0, s1), fmaxf(s2, s3));
      mx = fmaxf(mx, __shfl_xor(mx, 1));
      mx = fmaxf(mx, __shfl_xor(mx, 2));
      mx = fmaxf(mx, __shfl_xor(mx, 4));
      mx = fmaxf(mx, __shfl_xor(mx, 8));
      float mnew = fmaxf(m_i[i], mx);
      float alpha = __expf(m_i[i] - mnew);
      p[0][i] = __expf(s0 - mnew); p[1][i] = __expf(s1 - mnew);
      p[2][i] = __expf(s2 - mnew); p[3][i] = __expf(s3 - mnew);
      float sm = p[0][i] + p[1][i] + p[2][i] + p[3][i];
      sm += __shfl_xor(sm, 1); sm += __shfl_xor(sm, 2);
      sm += __shfl_xor(sm, 4); sm += __shfl_xor(sm, 8);
      l_i[i] = l_i[i] * alpha + sm;
      m_i[i] = mnew;
      o_acc[0][i] *= alpha; o_acc[1][i] *= alpha;
      o_acc[2][i] *= alpha; o_acc[3][i] *= alpha;
    }
#pragma unroll
    for (int nb = 0; nb < 4; ++nb)
#pragma unroll
      for (int i = 0; i < 4; ++i)
        QP[w * 16 + lq * 4 + i][nb * 16 + lr] = f2b(p[nb][i]);
    __syncthreads();

#pragma unroll
    for (int kk = 0; kk < 2; ++kk) {
      bf16x8 pf = *(const bf16x8*)&QP[w * 16 + lr][kk * 32 + lq * 8];
#pragma unroll
      for (int nb = 0; nb < 4; ++nb) {
        bf16x8 vf = *(const bf16x8*)&Vt[nb * 16 + lr][kk * 32 + lq * 8];
        o_acc[nb] = __builtin_amdgcn_mfma_f32_16x16x32_bf16(pf, vf, o_acc[nb], 0, 0, 0);
      }
    }
  }
#pragma unroll
  for (int i = 0; i < 4; ++i) {
    float inv = 1.0f / l_i[i];
    int row = qt * 64 + w * 16 + lq * 4 + i;
    int ob = (b * 2048 + row) * 1024 + h * 64;
#pragma unroll
    for (int nb = 0; nb < 4; ++nb)
      AO[ob + nb * 16 + lr] = f2b(o_acc[nb][i] * inv);
  }
}

// ---------------------------------------------------------------------------
// Kernel 3: out = ao @ w_out^T (bf16 MFMA NT, 64x64 tile). R3-verbatim.
// ---------------------------------------------------------------------------
__global__ __launch_bounds__(256) void k_gemm_out(const u16* __restrict__ A,
                                                  const void* __restrict__ Bv,
                                                  const int* __restrict__ flag,
                                                  void* __restrict__ Cv) {
  __shared__ u16 As[64][40];
  __shared__ u16 Bs[64][40];
  const int mode = flag[0];
  const int n0 = blockIdx.x * 64, m0 = blockIdx.y * 64;
  const int t = threadIdx.x, w = t >> 6, lane = t & 63;
  const int lr = lane & 15, lq = lane >> 4;
  f32x4 acc[4] = {};
  const int rA = t >> 2, cA = (t & 3) * 8;
  const int aoff = (m0 + rA) * 1024 + cA;
  const int boff = (n0 + rA) * 1024 + cA;
  for (int k0 = 0; k0 < 1024; k0 += 32) {
    __syncthreads();
    *(uint4*)&As[rA][cA] = *(const uint4*)(A + aoff + k0);
    if (mode == 0) {
      *(uint4*)&Bs[rA][cA] = *(const uint4*)((const u16*)Bv + boff + k0);
    } else {
      const float* Bf = (const float*)Bv;
#pragma unroll
      for (int e = 0; e < 8; ++e) Bs[rA][cA + e] = f2b(Bf[boff + k0 + e]);
    }
    __syncthreads();
    bf16x8 bf = *(const bf16x8*)&Bs[(w << 4) + lr][lq * 8];
#pragma unroll
    for (int mt = 0; mt < 4; ++mt) {
      bf16x8 af = *(const bf16x8*)&As[(mt << 4) + lr][lq * 8];
      acc[mt] = __builtin_amdgcn_mfma_f32_16x16x32_bf16(af, bf, acc[mt], 0, 0, 0);
    }
  }
  const int col = n0 + (w << 4) + lr;
  if (mode == 0) {
    u16* C = (u16*)Cv;
#pragma unroll
    for (int mt = 0; mt < 4; ++mt)
#pragma unroll
      for (int i = 0; i < 4; ++i)
        C[(m0 + mt * 16 + lq * 4 + i) * 1024 + col] = f2b(acc[mt][i]);
  } else {
    float* C = (float*)Cv;
#pragma unroll
    for (int mt = 0; mt < 4; ++mt)
#pragma unroll
      for (int i = 0; i < 4; ++i)
        C[(m0 + mt * 16 + lq * 4 + i) * 1024 + col] = acc[mt][i];
  }
}

// ---------------------------------------------------------------------------
extern "C" void kernel_launch(void* const* d_in, const int* in_sizes, int n_in,
                              void* d_out, int out_size, void* d_ws, size_t ws_size,
                              hipStream_t stream) {
  const void* x    = d_in[0];   // (4096,1024)
  const void* wqkv = d_in[1];   // (3072,1024)
  const void* wout = d_in[2];   // (1024,1024)

  // ws layout (R3-verbatim): [flag 256B][q 8.39MB][k 8.39MB][v^T 8.39MB][ao]
  int* flag = (int*)d_ws;
  u16* qb = (u16*)((char*)d_ws + 256);
  u16* kb = qb + 4194304;
  u16* vb = kb + 4194304;
  u16* ao = vb + 4194304;

  k_detect  <<<dim3(1), 256, 0, stream>>>((const u16*)x, flag);
  k_qkv_rope<<<dim3(48, 64), 256, 0, stream>>>(x, wqkv, flag, qb, kb, vb);
  k_attn    <<<dim3(32, 32), 256, 0, stream>>>(qb, kb, vb, ao);
  k_gemm_out<<<dim3(16, 64), 256, 0, stream>>>(ao, wout, flag, d_out);
}

// Round 9
// 271.516 us; speedup vs baseline: 2.6565x; 1.1614x over previous
//
#include <hip/hip_runtime.h>
#include <stdint.h>

typedef uint16_t u16;
typedef __attribute__((ext_vector_type(8))) short bf16x8;
typedef __attribute__((ext_vector_type(4))) float f32x4;

__device__ inline u16 f2b(float f) {          // fp32 -> bf16 RNE
  uint32_t u = __float_as_uint(f);
  u += 0x7FFF + ((u >> 16) & 1);
  return (u16)(u >> 16);
}
__device__ inline float b2f(u16 h) {          // bf16 -> fp32 exact
  return __uint_as_float(((uint32_t)h) << 16);
}

// ---------------------------------------------------------------------------
// Dtype probe (R3-verbatim): mode 0 = bf16 inputs, 1 = fp32.
// ---------------------------------------------------------------------------
__global__ void k_detect(const u16* __restrict__ X, int* __restrict__ flag) {
  __shared__ int cnt;
  const int t = threadIdx.x;
  if (t == 0) cnt = 0;
  __syncthreads();
  float av = fabsf(b2f(X[t * 2]));
  int wild = (av < 1000.0f) ? 0 : 1;
  atomicAdd(&cnt, wild);
  __syncthreads();
  if (t == 0) flag[0] = (cnt > 16) ? 1 : 0;
}

// ---------------------------------------------------------------------------
// Kernel 1: qkv = x @ w_qkv^T (bf16 MFMA NT, 64x64 tile), RoPE in epilogue
// with fast transcendentals. R8-verbatim.
// ---------------------------------------------------------------------------
__global__ __launch_bounds__(256) void k_qkv_rope(const void* __restrict__ Xv,
                                                  const void* __restrict__ Wv,
                                                  const int* __restrict__ flag,
                                                  u16* __restrict__ Qo,
                                                  u16* __restrict__ Ko,
                                                  u16* __restrict__ Vo) {
  __shared__ u16 As[64][40];
  __shared__ u16 Bs[64][40];
  __shared__ float Cs[64][66];
  const int mode = flag[0];
  const int n0 = blockIdx.x * 64, m0 = blockIdx.y * 64;
  const int t = threadIdx.x, w = t >> 6, lane = t & 63;
  const int lr = lane & 15, lq = lane >> 4;
  f32x4 acc[4] = {};
  const int rA = t >> 2, cA = (t & 3) * 8;
  const int aoff = (m0 + rA) * 1024 + cA;
  const int boff = (n0 + rA) * 1024 + cA;
  for (int k0 = 0; k0 < 1024; k0 += 32) {
    __syncthreads();
    if (mode == 0) {
      *(uint4*)&As[rA][cA] = *(const uint4*)((const u16*)Xv + aoff + k0);
      *(uint4*)&Bs[rA][cA] = *(const uint4*)((const u16*)Wv + boff + k0);
    } else {
      const float* Xf = (const float*)Xv;
      const float* Wf = (const float*)Wv;
#pragma unroll
      for (int e = 0; e < 8; ++e) {
        As[rA][cA + e] = f2b(Xf[aoff + k0 + e]);
        Bs[rA][cA + e] = f2b(Wf[boff + k0 + e]);
      }
    }
    __syncthreads();
    bf16x8 bf = *(const bf16x8*)&Bs[(w << 4) + lr][lq * 8];
#pragma unroll
    for (int mt = 0; mt < 4; ++mt) {
      bf16x8 af = *(const bf16x8*)&As[(mt << 4) + lr][lq * 8];
      acc[mt] = __builtin_amdgcn_mfma_f32_16x16x32_bf16(af, bf, acc[mt], 0, 0, 0);
    }
  }
  {
    const int col = (w << 4) + lr;
#pragma unroll
    for (int mt = 0; mt < 4; ++mt)
#pragma unroll
      for (int i = 0; i < 4; ++i)
        Cs[mt * 16 + lq * 4 + i][col] = acc[mt][i];
  }
  __syncthreads();
  const int e = n0 >> 10;          // 0=q 1=k 2=v
  const int h = (n0 >> 6) & 15;
  if (e == 2) {
    const int sx = t & 63, dh0 = (t >> 6) * 16;
    const int m = m0 + sx, b = m >> 11, s = m & 2047;
    const long hb = (long)(b * 16 + h) * 64;
#pragma unroll
    for (int u = 0; u < 16; ++u) {
      int dh = dh0 + u;
      Vo[(hb + dh) * 2048 + s] = f2b(Cs[sx][dh]);
    }
  } else {
    const int r = t >> 2, dh0 = (t & 3) * 16;
    const int m = m0 + r, b = m >> 11, s = m & 2047;
    const int obase = ((b * 16 + h) * 2048 + s) * 64;
    u16* O = (e == 0) ? Qo : Ko;
#pragma unroll
    for (int u = 0; u < 16; ++u) {
      int dh = dh0 + u;
      float v  = Cs[r][dh];
      float vp = Cs[r][dh ^ 32];
      float sign = (dh < 32) ? -1.0f : 1.0f;
      float fr  = __expf((float)(dh & 31) * -0.28782314f);
      float ang = (float)s * fr;
      float sn = __sinf(ang), cs = __cosf(ang);
      O[obase + dh] = f2b(v * cs + sign * vp * sn);
    }
  }
}

// ---------------------------------------------------------------------------
// Kernel 2: causal flash attention, bf16 MFMA. THIS ROUND'S ONLY CHANGE:
// S^T-form scores (swapped mfma operands) -> per-lane row stats, 2+2 shuffle
// softmax, packed b64 P-writes, 3rd barrier -> wave-local lgkmcnt wait.
// ---------------------------------------------------------------------------
__global__ __launch_bounds__(256) void k_attn(const u16* __restrict__ Q,
                                              const u16* __restrict__ K,
                                              const u16* __restrict__ V,
                                              u16* __restrict__ AO) {
  __shared__ u16 QP[64][72];   // Q tile, then P tile (wave-private 16-row blocks)
  __shared__ u16 Ks[64][72];
  __shared__ u16 Vt[64][72];
  const int qt = 31 - blockIdx.x;
  const int bh = blockIdx.y;
  const int b = bh >> 4, h = bh & 15;
  const u16* Qg = Q + (bh * 2048 + qt * 64) * 64;
  const u16* Kg = K + bh * 2048 * 64;
  const u16* Vg = V + (long)bh * 64 * 2048;
  const int t = threadIdx.x, w = t >> 6, lane = t & 63;
  const int lr = lane & 15, lq = lane >> 4;
  const int lq4 = lq * 4;
  const int base16 = lane & 48;    // lq*16: shuffle base for row-stat broadcast
  const int r0 = t >> 3, c0 = (t & 7) * 8;

  *(uint4*)&QP[r0][c0]      = *(const uint4*)&Qg[r0 * 64 + c0];
  *(uint4*)&QP[r0 + 32][c0] = *(const uint4*)&Qg[(r0 + 32) * 64 + c0];
  __syncthreads();
  bf16x8 qf[2];
#pragma unroll
  for (int kk = 0; kk < 2; ++kk)
    qf[kk] = *(const bf16x8*)&QP[w * 16 + lr][kk * 32 + lq * 8];

  // per-lane online-softmax state for q-row (w*16 + lr)
  float m_i = -3.0e4f, l_i = 0.f;
  f32x4 o_acc[4] = {};   // C-layout: row = w*16 + lq4+i, col dh = nb*16+lr

  const int qrow_l = w * 16 + lr;   // this lane's q-row (local to 64-tile)

  for (int kt = 0; kt <= qt; ++kt) {
    __syncthreads();   // prev Ks/Vt reads done (cross-wave staging)
    *(uint4*)&Ks[r0][c0]      = *(const uint4*)&Kg[(kt * 64 + r0) * 64 + c0];
    *(uint4*)&Ks[r0 + 32][c0] = *(const uint4*)&Kg[(kt * 64 + r0 + 32) * 64 + c0];
    *(uint4*)&Vt[r0][c0]      = *(const uint4*)&Vg[r0 * 2048 + kt * 64 + c0];
    *(uint4*)&Vt[r0 + 32][c0] = *(const uint4*)&Vg[(r0 + 32) * 2048 + kt * 64 + c0];
    __syncthreads();

    // S^T = K Q^T : D[m = kpos (mb*16 + lq4+i)][n = qrow (lr)]
    f32x4 sa[4] = {};
#pragma unroll
    for (int mb = 0; mb < 4; ++mb)
#pragma unroll
      for (int kk = 0; kk < 2; ++kk) {
        bf16x8 kf = *(const bf16x8*)&Ks[mb * 16 + lr][kk * 32 + lq * 8];
        sa[mb] = __builtin_amdgcn_mfma_f32_16x16x32_bf16(kf, qf[kk], sa[mb], 0, 0, 0);
      }

    // online softmax: lane owns one q-row, 16 k-values in regs
    float sc[4][4];
    float m_new = m_i;
#pragma unroll
    for (int mb = 0; mb < 4; ++mb)
#pragma unroll
      for (int i = 0; i < 4; ++i) {
        float sv = sa[mb][i] * 0.125f;
        if (kt == qt && (mb * 16 + lq4 + i) > qrow_l) sv = -3.0e4f;  // causal
        sc[mb][i] = sv;
        m_new = fmaxf(m_new, sv);
      }
    m_new = fmaxf(m_new, __shfl_xor(m_new, 16));
    m_new = fmaxf(m_new, __shfl_xor(m_new, 32));
    float alpha = __expf(m_i - m_new);
    m_i = m_new;
    float p[4][4], sm = 0.f;
#pragma unroll
    for (int mb = 0; mb < 4; ++mb)
#pragma unroll
      for (int i = 0; i < 4; ++i) { p[mb][i] = __expf(sc[mb][i] - m_new); sm += p[mb][i]; }
    sm += __shfl_xor(sm, 16);
    sm += __shfl_xor(sm, 32);
    l_i = l_i * alpha + sm;

    // P -> LDS (wave-private rows), packed b64: QP[w*16+lr][mb*16+lq4 .. +4)
#pragma unroll
    for (int mb = 0; mb < 4; ++mb) {
      uint2 pk;
      pk.x = (uint32_t)f2b(p[mb][0]) | ((uint32_t)f2b(p[mb][1]) << 16);
      pk.y = (uint32_t)f2b(p[mb][2]) | ((uint32_t)f2b(p[mb][3]) << 16);
      *(uint2*)&QP[w * 16 + lr][mb * 16 + lq4] = pk;
    }

    // rescale o_acc by alpha of its rows (stats live at lane lr = lq4+i)
#pragma unroll
    for (int i = 0; i < 4; ++i) {
      float ai = __shfl(alpha, base16 | (lq4 + i));
      o_acc[0][i] *= ai; o_acc[1][i] *= ai;
      o_acc[2][i] *= ai; o_acc[3][i] *= ai;
    }

    // wave-private P round-trip: DS pipe is in-order per wave; drain lgkm
    asm volatile("s_waitcnt lgkmcnt(0)" ::: "memory");

    // O += P V : A = P rows (wave-private), B = Vt rows (dh)
#pragma unroll
    for (int kk = 0; kk < 2; ++kk) {
      bf16x8 pf = *(const bf16x8*)&QP[w * 16 + lr][kk * 32 + lq * 8];
#pragma unroll
      for (int nb = 0; nb < 4; ++nb) {
        bf16x8 vf = *(const bf16x8*)&Vt[nb * 16 + lr][kk * 32 + lq * 8];
        o_acc[nb] = __builtin_amdgcn_mfma_f32_16x16x32_bf16(pf, vf, o_acc[nb], 0, 0, 0);
      }
    }
  }
  // epilogue: row = qt*64 + w*16 + lq4+i, col dh = nb*16+lr
  float linv = 1.0f / l_i;
#pragma unroll
  for (int i = 0; i < 4; ++i) {
    float inv = __shfl(linv, base16 | (lq4 + i));
    int row = qt * 64 + w * 16 + lq4 + i;
    int ob = (b * 2048 + row) * 1024 + h * 64;
#pragma unroll
    for (int nb = 0; nb < 4; ++nb)
      AO[ob + nb * 16 + lr] = f2b(o_acc[nb][i] * inv);
  }
}

// ---------------------------------------------------------------------------
// Kernel 3: out = ao @ w_out^T (bf16 MFMA NT, 64x64 tile). R8-verbatim.
// ---------------------------------------------------------------------------
__global__ __launch_bounds__(256) void k_gemm_out(const u16* __restrict__ A,
                                                  const void* __restrict__ Bv,
                                                  const int* __restrict__ flag,
                                                  void* __restrict__ Cv) {
  __shared__ u16 As[64][40];
  __shared__ u16 Bs[64][40];
  const int mode = flag[0];
  const int n0 = blockIdx.x * 64, m0 = blockIdx.y * 64;
  const int t = threadIdx.x, w = t >> 6, lane = t & 63;
  const int lr = lane & 15, lq = lane >> 4;
  f32x4 acc[4] = {};
  const int rA = t >> 2, cA = (t & 3) * 8;
  const int aoff = (m0 + rA) * 1024 + cA;
  const int boff = (n0 + rA) * 1024 + cA;
  for (int k0 = 0; k0 < 1024; k0 += 32) {
    __syncthreads();
    *(uint4*)&As[rA][cA] = *(const uint4*)(A + aoff + k0);
    if (mode == 0) {
      *(uint4*)&Bs[rA][cA] = *(const uint4*)((const u16*)Bv + boff + k0);
    } else {
      const float* Bf = (const float*)Bv;
#pragma unroll
      for (int e = 0; e < 8; ++e) Bs[rA][cA + e] = f2b(Bf[boff + k0 + e]);
    }
    __syncthreads();
    bf16x8 bf = *(const bf16x8*)&Bs[(w << 4) + lr][lq * 8];
#pragma unroll
    for (int mt = 0; mt < 4; ++mt) {
      bf16x8 af = *(const bf16x8*)&As[(mt << 4) + lr][lq * 8];
      acc[mt] = __builtin_amdgcn_mfma_f32_16x16x32_bf16(af, bf, acc[mt], 0, 0, 0);
    }
  }
  const int col = n0 + (w << 4) + lr;
  if (mode == 0) {
    u16* C = (u16*)Cv;
#pragma unroll
    for (int mt = 0; mt < 4; ++mt)
#pragma unroll
      for (int i = 0; i < 4; ++i)
        C[(m0 + mt * 16 + lq * 4 + i) * 1024 + col] = f2b(acc[mt][i]);
  } else {
    float* C = (float*)Cv;
#pragma unroll
    for (int mt = 0; mt < 4; ++mt)
#pragma unroll
      for (int i = 0; i < 4; ++i)
        C[(m0 + mt * 16 + lq * 4 + i) * 1024 + col] = acc[mt][i];
  }
}

// ---------------------------------------------------------------------------
extern "C" void kernel_launch(void* const* d_in, const int* in_sizes, int n_in,
                              void* d_out, int out_size, void* d_ws, size_t ws_size,
                              hipStream_t stream) {
  const void* x    = d_in[0];   // (4096,1024)
  const void* wqkv = d_in[1];   // (3072,1024)
  const void* wout = d_in[2];   // (1024,1024)

  // ws layout (R3/R8-verbatim): [flag 256B][q 8.39MB][k 8.39MB][v^T 8.39MB][ao]
  int* flag = (int*)d_ws;
  u16* qb = (u16*)((char*)d_ws + 256);
  u16* kb = qb + 4194304;
  u16* vb = kb + 4194304;
  u16* ao = vb + 4194304;

  k_detect  <<<dim3(1), 256, 0, stream>>>((const u16*)x, flag);
  k_qkv_rope<<<dim3(48, 64), 256, 0, stream>>>(x, wqkv, flag, qb, kb, vb);
  k_attn    <<<dim3(32, 32), 256, 0, stream>>>(qb, kb, vb, ao);
  k_gemm_out<<<dim3(16, 64), 256, 0, stream>>>(ao, wout, flag, d_out);
}

// Round 10
// 247.815 us; speedup vs baseline: 2.9105x; 1.0956x over previous
//
#include <hip/hip_runtime.h>
#include <stdint.h>

typedef uint16_t u16;
typedef __attribute__((ext_vector_type(8))) short bf16x8;
typedef __attribute__((ext_vector_type(4))) float f32x4;

__device__ inline u16 f2b(float f) {          // fp32 -> bf16 RNE
  uint32_t u = __float_as_uint(f);
  u += 0x7FFF + ((u >> 16) & 1);
  return (u16)(u >> 16);
}
__device__ inline float b2f(u16 h) {          // bf16 -> fp32 exact
  return __uint_as_float(((uint32_t)h) << 16);
}

// ---------------------------------------------------------------------------
// Dtype probe (R3-verbatim): mode 0 = bf16 inputs, 1 = fp32.
// ---------------------------------------------------------------------------
__global__ void k_detect(const u16* __restrict__ X, int* __restrict__ flag) {
  __shared__ int cnt;
  const int t = threadIdx.x;
  if (t == 0) cnt = 0;
  __syncthreads();
  float av = fabsf(b2f(X[t * 2]));
  int wild = (av < 1000.0f) ? 0 : 1;
  atomicAdd(&cnt, wild);
  __syncthreads();
  if (t == 0) flag[0] = (cnt > 16) ? 1 : 0;
}

// ---------------------------------------------------------------------------
// Kernel 1: qkv = x @ w_qkv^T. THIS ROUND'S ONLY CHANGE: e-fused 64-tile —
// one block = one (m-tile, head), staging A once + q/k/v B-tiles per K-step
// (12 MFMA/wave per barrier pair vs 4). Epilogue = serial e-loop over the
// R9-proven Cs/RoPE/V-transpose code. Grid 48x64 -> 16x64.
// ---------------------------------------------------------------------------
__global__ __launch_bounds__(256) void k_qkv_rope(const void* __restrict__ Xv,
                                                  const void* __restrict__ Wv,
                                                  const int* __restrict__ flag,
                                                  u16* __restrict__ Qo,
                                                  u16* __restrict__ Ko,
                                                  u16* __restrict__ Vo) {
  __shared__ u16 As[64][40];
  __shared__ u16 Bs[3][64][40];
  __shared__ float Cs[64][66];
  const int mode = flag[0];
  const int h = blockIdx.x;               // head 0..15
  const int n0h = h * 64;                 // W row within each e-chunk
  const int m0 = blockIdx.y * 64;
  const int t = threadIdx.x, w = t >> 6, lane = t & 63;
  const int lr = lane & 15, lq = lane >> 4;
  f32x4 acc[3][4] = {};
  const int rA = t >> 2, cA = (t & 3) * 8;
  const int aoff = (m0 + rA) * 1024 + cA;
  const int boff0 = (n0h + rA) * 1024 + cA;             // e stride = 1024*1024
  for (int k0 = 0; k0 < 1024; k0 += 32) {
    __syncthreads();
    if (mode == 0) {
      *(uint4*)&As[rA][cA]    = *(const uint4*)((const u16*)Xv + aoff + k0);
      *(uint4*)&Bs[0][rA][cA] = *(const uint4*)((const u16*)Wv + boff0 + k0);
      *(uint4*)&Bs[1][rA][cA] = *(const uint4*)((const u16*)Wv + boff0 + 1048576 + k0);
      *(uint4*)&Bs[2][rA][cA] = *(const uint4*)((const u16*)Wv + boff0 + 2097152 + k0);
    } else {
      const float* Xf = (const float*)Xv;
      const float* Wf = (const float*)Wv;
#pragma unroll
      for (int ee = 0; ee < 8; ++ee) {
        As[rA][cA + ee]    = f2b(Xf[aoff + k0 + ee]);
        Bs[0][rA][cA + ee] = f2b(Wf[boff0 + k0 + ee]);
        Bs[1][rA][cA + ee] = f2b(Wf[boff0 + 1048576 + k0 + ee]);
        Bs[2][rA][cA + ee] = f2b(Wf[boff0 + 2097152 + k0 + ee]);
      }
    }
    __syncthreads();
    bf16x8 bf[3];
#pragma unroll
    for (int e = 0; e < 3; ++e)
      bf[e] = *(const bf16x8*)&Bs[e][(w << 4) + lr][lq * 8];
#pragma unroll
    for (int mt = 0; mt < 4; ++mt) {
      bf16x8 af = *(const bf16x8*)&As[(mt << 4) + lr][lq * 8];
#pragma unroll
      for (int e = 0; e < 3; ++e)
        acc[e][mt] = __builtin_amdgcn_mfma_f32_16x16x32_bf16(af, bf[e], acc[e][mt], 0, 0, 0);
    }
  }

  // epilogue: serial over e, reusing Cs (sync-fenced). R9-proven math.
  for (int e = 0; e < 3; ++e) {
    __syncthreads();   // prior Cs reads (or last MFMA) done
    {
      const int col = (w << 4) + lr;
#pragma unroll
      for (int mt = 0; mt < 4; ++mt)
#pragma unroll
        for (int i = 0; i < 4; ++i)
          Cs[mt * 16 + lq * 4 + i][col] = acc[e][mt][i];
    }
    __syncthreads();
    if (e == 2) {
      const int sx = t & 63, dh0 = (t >> 6) * 16;
      const int m = m0 + sx, b = m >> 11, s = m & 2047;
      const long hb = (long)(b * 16 + h) * 64;
#pragma unroll
      for (int u = 0; u < 16; ++u) {
        int dh = dh0 + u;
        Vo[(hb + dh) * 2048 + s] = f2b(Cs[sx][dh]);
      }
    } else {
      const int r = t >> 2, dh0 = (t & 3) * 16;
      const int m = m0 + r, b = m >> 11, s = m & 2047;
      const int obase = ((b * 16 + h) * 2048 + s) * 64;
      u16* O = (e == 0) ? Qo : Ko;
#pragma unroll
      for (int u = 0; u < 16; ++u) {
        int dh = dh0 + u;
        float v  = Cs[r][dh];
        float vp = Cs[r][dh ^ 32];
        float sign = (dh < 32) ? -1.0f : 1.0f;
        float fr  = __expf((float)(dh & 31) * -0.28782314f);
        float ang = (float)s * fr;
        float sn = __sinf(ang), cs = __cosf(ang);
        O[obase + dh] = f2b(v * cs + sign * vp * sn);
      }
    }
  }
}

// ---------------------------------------------------------------------------
// Kernel 2: causal flash attention, bf16 MFMA, S^T-form softmax (R9-verbatim).
// ---------------------------------------------------------------------------
__global__ __launch_bounds__(256) void k_attn(const u16* __restrict__ Q,
                                              const u16* __restrict__ K,
                                              const u16* __restrict__ V,
                                              u16* __restrict__ AO) {
  __shared__ u16 QP[64][72];   // Q tile, then P tile (wave-private 16-row blocks)
  __shared__ u16 Ks[64][72];
  __shared__ u16 Vt[64][72];
  const int qt = 31 - blockIdx.x;
  const int bh = blockIdx.y;
  const int b = bh >> 4, h = bh & 15;
  const u16* Qg = Q + (bh * 2048 + qt * 64) * 64;
  const u16* Kg = K + bh * 2048 * 64;
  const u16* Vg = V + (long)bh * 64 * 2048;
  const int t = threadIdx.x, w = t >> 6, lane = t & 63;
  const int lr = lane & 15, lq = lane >> 4;
  const int lq4 = lq * 4;
  const int base16 = lane & 48;
  const int r0 = t >> 3, c0 = (t & 7) * 8;

  *(uint4*)&QP[r0][c0]      = *(const uint4*)&Qg[r0 * 64 + c0];
  *(uint4*)&QP[r0 + 32][c0] = *(const uint4*)&Qg[(r0 + 32) * 64 + c0];
  __syncthreads();
  bf16x8 qf[2];
#pragma unroll
  for (int kk = 0; kk < 2; ++kk)
    qf[kk] = *(const bf16x8*)&QP[w * 16 + lr][kk * 32 + lq * 8];

  float m_i = -3.0e4f, l_i = 0.f;
  f32x4 o_acc[4] = {};
  const int qrow_l = w * 16 + lr;

  for (int kt = 0; kt <= qt; ++kt) {
    __syncthreads();
    *(uint4*)&Ks[r0][c0]      = *(const uint4*)&Kg[(kt * 64 + r0) * 64 + c0];
    *(uint4*)&Ks[r0 + 32][c0] = *(const uint4*)&Kg[(kt * 64 + r0 + 32) * 64 + c0];
    *(uint4*)&Vt[r0][c0]      = *(const uint4*)&Vg[r0 * 2048 + kt * 64 + c0];
    *(uint4*)&Vt[r0 + 32][c0] = *(const uint4*)&Vg[(r0 + 32) * 2048 + kt * 64 + c0];
    __syncthreads();

    f32x4 sa[4] = {};
#pragma unroll
    for (int mb = 0; mb < 4; ++mb)
#pragma unroll
      for (int kk = 0; kk < 2; ++kk) {
        bf16x8 kf = *(const bf16x8*)&Ks[mb * 16 + lr][kk * 32 + lq * 8];
        sa[mb] = __builtin_amdgcn_mfma_f32_16x16x32_bf16(kf, qf[kk], sa[mb], 0, 0, 0);
      }

    float sc[4][4];
    float m_new = m_i;
#pragma unroll
    for (int mb = 0; mb < 4; ++mb)
#pragma unroll
      for (int i = 0; i < 4; ++i) {
        float sv = sa[mb][i] * 0.125f;
        if (kt == qt && (mb * 16 + lq4 + i) > qrow_l) sv = -3.0e4f;
        sc[mb][i] = sv;
        m_new = fmaxf(m_new, sv);
      }
    m_new = fmaxf(m_new, __shfl_xor(m_new, 16));
    m_new = fmaxf(m_new, __shfl_xor(m_new, 32));
    float alpha = __expf(m_i - m_new);
    m_i = m_new;
    float p[4][4], sm = 0.f;
#pragma unroll
    for (int mb = 0; mb < 4; ++mb)
#pragma unroll
      for (int i = 0; i < 4; ++i) { p[mb][i] = __expf(sc[mb][i] - m_new); sm += p[mb][i]; }
    sm += __shfl_xor(sm, 16);
    sm += __shfl_xor(sm, 32);
    l_i = l_i * alpha + sm;

#pragma unroll
    for (int mb = 0; mb < 4; ++mb) {
      uint2 pk;
      pk.x = (uint32_t)f2b(p[mb][0]) | ((uint32_t)f2b(p[mb][1]) << 16);
      pk.y = (uint32_t)f2b(p[mb][2]) | ((uint32_t)f2b(p[mb][3]) << 16);
      *(uint2*)&QP[w * 16 + lr][mb * 16 + lq4] = pk;
    }

#pragma unroll
    for (int i = 0; i < 4; ++i) {
      float ai = __shfl(alpha, base16 | (lq4 + i));
      o_acc[0][i] *= ai; o_acc[1][i] *= ai;
      o_acc[2][i] *= ai; o_acc[3][i] *= ai;
    }

    asm volatile("s_waitcnt lgkmcnt(0)" ::: "memory");

#pragma unroll
    for (int kk = 0; kk < 2; ++kk) {
      bf16x8 pf = *(const bf16x8*)&QP[w * 16 + lr][kk * 32 + lq * 8];
#pragma unroll
      for (int nb = 0; nb < 4; ++nb) {
        bf16x8 vf = *(const bf16x8*)&Vt[nb * 16 + lr][kk * 32 + lq * 8];
        o_acc[nb] = __builtin_amdgcn_mfma_f32_16x16x32_bf16(pf, vf, o_acc[nb], 0, 0, 0);
      }
    }
  }
  float linv = 1.0f / l_i;
#pragma unroll
  for (int i = 0; i < 4; ++i) {
    float inv = __shfl(linv, base16 | (lq4 + i));
    int row = qt * 64 + w * 16 + lq4 + i;
    int ob = (b * 2048 + row) * 1024 + h * 64;
#pragma unroll
    for (int nb = 0; nb < 4; ++nb)
      AO[ob + nb * 16 + lr] = f2b(o_acc[nb][i] * inv);
  }
}

// ---------------------------------------------------------------------------
// Kernel 3: out = ao @ w_out^T (bf16 MFMA NT, 64x64 tile). R8-verbatim.
// ---------------------------------------------------------------------------
__global__ __launch_bounds__(256) void k_gemm_out(const u16* __restrict__ A,
                                                  const void* __restrict__ Bv,
                                                  const int* __restrict__ flag,
                                                  void* __restrict__ Cv) {
  __shared__ u16 As[64][40];
  __shared__ u16 Bs[64][40];
  const int mode = flag[0];
  const int n0 = blockIdx.x * 64, m0 = blockIdx.y * 64;
  const int t = threadIdx.x, w = t >> 6, lane = t & 63;
  const int lr = lane & 15, lq = lane >> 4;
  f32x4 acc[4] = {};
  const int rA = t >> 2, cA = (t & 3) * 8;
  const int aoff = (m0 + rA) * 1024 + cA;
  const int boff = (n0 + rA) * 1024 + cA;
  for (int k0 = 0; k0 < 1024; k0 += 32) {
    __syncthreads();
    *(uint4*)&As[rA][cA] = *(const uint4*)(A + aoff + k0);
    if (mode == 0) {
      *(uint4*)&Bs[rA][cA] = *(const uint4*)((const u16*)Bv + boff + k0);
    } else {
      const float* Bf = (const float*)Bv;
#pragma unroll
      for (int e = 0; e < 8; ++e) Bs[rA][cA + e] = f2b(Bf[boff + k0 + e]);
    }
    __syncthreads();
    bf16x8 bf = *(const bf16x8*)&Bs[(w << 4) + lr][lq * 8];
#pragma unroll
    for (int mt = 0; mt < 4; ++mt) {
      bf16x8 af = *(const bf16x8*)&As[(mt << 4) + lr][lq * 8];
      acc[mt] = __builtin_amdgcn_mfma_f32_16x16x32_bf16(af, bf, acc[mt], 0, 0, 0);
    }
  }
  const int col = n0 + (w << 4) + lr;
  if (mode == 0) {
    u16* C = (u16*)Cv;
#pragma unroll
    for (int mt = 0; mt < 4; ++mt)
#pragma unroll
      for (int i = 0; i < 4; ++i)
        C[(m0 + mt * 16 + lq * 4 + i) * 1024 + col] = f2b(acc[mt][i]);
  } else {
    float* C = (float*)Cv;
#pragma unroll
    for (int mt = 0; mt < 4; ++mt)
#pragma unroll
      for (int i = 0; i < 4; ++i)
        C[(m0 + mt * 16 + lq * 4 + i) * 1024 + col] = acc[mt][i];
  }
}

// ---------------------------------------------------------------------------
extern "C" void kernel_launch(void* const* d_in, const int* in_sizes, int n_in,
                              void* d_out, int out_size, void* d_ws, size_t ws_size,
                              hipStream_t stream) {
  const void* x    = d_in[0];   // (4096,1024)
  const void* wqkv = d_in[1];   // (3072,1024)
  const void* wout = d_in[2];   // (1024,1024)

  // ws layout (R3/R8-verbatim): [flag 256B][q 8.39MB][k 8.39MB][v^T 8.39MB][ao]
  int* flag = (int*)d_ws;
  u16* qb = (u16*)((char*)d_ws + 256);
  u16* kb = qb + 4194304;
  u16* vb = kb + 4194304;
  u16* ao = vb + 4194304;

  k_detect  <<<dim3(1), 256, 0, stream>>>((const u16*)x, flag);
  k_qkv_rope<<<dim3(16, 64), 256, 0, stream>>>(x, wqkv, flag, qb, kb, vb);
  k_attn    <<<dim3(32, 32), 256, 0, stream>>>(qb, kb, vb, ao);
  k_gemm_out<<<dim3(16, 64), 256, 0, stream>>>(ao, wout, flag, d_out);
}

// Round 11
// 235.605 us; speedup vs baseline: 3.0614x; 1.0518x over previous
//
#include <hip/hip_runtime.h>
#include <stdint.h>

typedef uint16_t u16;
typedef __attribute__((ext_vector_type(8))) short bf16x8;
typedef __attribute__((ext_vector_type(4))) float f32x4;

__device__ inline u16 f2b(float f) {          // fp32 -> bf16 RNE
  uint32_t u = __float_as_uint(f);
  u += 0x7FFF + ((u >> 16) & 1);
  return (u16)(u >> 16);
}
__device__ inline float b2f(u16 h) {          // bf16 -> fp32 exact
  return __uint_as_float(((uint32_t)h) << 16);
}

// ---------------------------------------------------------------------------
// Dtype probe (R3-verbatim): mode 0 = bf16 inputs, 1 = fp32.
// ---------------------------------------------------------------------------
__global__ void k_detect(const u16* __restrict__ X, int* __restrict__ flag) {
  __shared__ int cnt;
  const int t = threadIdx.x;
  if (t == 0) cnt = 0;
  __syncthreads();
  float av = fabsf(b2f(X[t * 2]));
  int wild = (av < 1000.0f) ? 0 : 1;
  atomicAdd(&cnt, wild);
  __syncthreads();
  if (t == 0) flag[0] = (cnt > 16) ? 1 : 0;
}

// ---------------------------------------------------------------------------
// Kernel 1: qkv = x @ w_qkv^T, e-fused 64-tile (R10-verbatim).
// ---------------------------------------------------------------------------
__global__ __launch_bounds__(256) void k_qkv_rope(const void* __restrict__ Xv,
                                                  const void* __restrict__ Wv,
                                                  const int* __restrict__ flag,
                                                  u16* __restrict__ Qo,
                                                  u16* __restrict__ Ko,
                                                  u16* __restrict__ Vo) {
  __shared__ u16 As[64][40];
  __shared__ u16 Bs[3][64][40];
  __shared__ float Cs[64][66];
  const int mode = flag[0];
  const int h = blockIdx.x;               // head 0..15
  const int n0h = h * 64;
  const int m0 = blockIdx.y * 64;
  const int t = threadIdx.x, w = t >> 6, lane = t & 63;
  const int lr = lane & 15, lq = lane >> 4;
  f32x4 acc[3][4] = {};
  const int rA = t >> 2, cA = (t & 3) * 8;
  const int aoff = (m0 + rA) * 1024 + cA;
  const int boff0 = (n0h + rA) * 1024 + cA;
  for (int k0 = 0; k0 < 1024; k0 += 32) {
    __syncthreads();
    if (mode == 0) {
      *(uint4*)&As[rA][cA]    = *(const uint4*)((const u16*)Xv + aoff + k0);
      *(uint4*)&Bs[0][rA][cA] = *(const uint4*)((const u16*)Wv + boff0 + k0);
      *(uint4*)&Bs[1][rA][cA] = *(const uint4*)((const u16*)Wv + boff0 + 1048576 + k0);
      *(uint4*)&Bs[2][rA][cA] = *(const uint4*)((const u16*)Wv + boff0 + 2097152 + k0);
    } else {
      const float* Xf = (const float*)Xv;
      const float* Wf = (const float*)Wv;
#pragma unroll
      for (int ee = 0; ee < 8; ++ee) {
        As[rA][cA + ee]    = f2b(Xf[aoff + k0 + ee]);
        Bs[0][rA][cA + ee] = f2b(Wf[boff0 + k0 + ee]);
        Bs[1][rA][cA + ee] = f2b(Wf[boff0 + 1048576 + k0 + ee]);
        Bs[2][rA][cA + ee] = f2b(Wf[boff0 + 2097152 + k0 + ee]);
      }
    }
    __syncthreads();
    bf16x8 bf[3];
#pragma unroll
    for (int e = 0; e < 3; ++e)
      bf[e] = *(const bf16x8*)&Bs[e][(w << 4) + lr][lq * 8];
#pragma unroll
    for (int mt = 0; mt < 4; ++mt) {
      bf16x8 af = *(const bf16x8*)&As[(mt << 4) + lr][lq * 8];
#pragma unroll
      for (int e = 0; e < 3; ++e)
        acc[e][mt] = __builtin_amdgcn_mfma_f32_16x16x32_bf16(af, bf[e], acc[e][mt], 0, 0, 0);
    }
  }
  for (int e = 0; e < 3; ++e) {
    __syncthreads();
    {
      const int col = (w << 4) + lr;
#pragma unroll
      for (int mt = 0; mt < 4; ++mt)
#pragma unroll
        for (int i = 0; i < 4; ++i)
          Cs[mt * 16 + lq * 4 + i][col] = acc[e][mt][i];
    }
    __syncthreads();
    if (e == 2) {
      const int sx = t & 63, dh0 = (t >> 6) * 16;
      const int m = m0 + sx, b = m >> 11, s = m & 2047;
      const long hb = (long)(b * 16 + h) * 64;
#pragma unroll
      for (int u = 0; u < 16; ++u) {
        int dh = dh0 + u;
        Vo[(hb + dh) * 2048 + s] = f2b(Cs[sx][dh]);
      }
    } else {
      const int r = t >> 2, dh0 = (t & 3) * 16;
      const int m = m0 + r, b = m >> 11, s = m & 2047;
      const int obase = ((b * 16 + h) * 2048 + s) * 64;
      u16* O = (e == 0) ? Qo : Ko;
#pragma unroll
      for (int u = 0; u < 16; ++u) {
        int dh = dh0 + u;
        float v  = Cs[r][dh];
        float vp = Cs[r][dh ^ 32];
        float sign = (dh < 32) ? -1.0f : 1.0f;
        float fr  = __expf((float)(dh & 31) * -0.28782314f);
        float ang = (float)s * fr;
        float sn = __sinf(ang), cs = __cosf(ang);
        O[obase + dh] = f2b(v * cs + sign * vp * sn);
      }
    }
  }
}

// ---------------------------------------------------------------------------
// Per-tile attention body (R9-proven math, factored; per-tile qt/state).
// ---------------------------------------------------------------------------
__device__ __forceinline__ void attn_tile(u16 QP[64][72], u16 Ks[64][72],
                                          u16 Vt[64][72], const bf16x8 qf[2],
                                          f32x4 o_acc[4], float& m_i, float& l_i,
                                          int kt, int qt_tile, int w, int lr,
                                          int lq, int lq4, int base16, int qrow_l) {
  // S^T = K Q^T : D[m = kpos (mb*16 + lq4+i)][n = qrow (lr)]
  f32x4 sa[4] = {};
#pragma unroll
  for (int mb = 0; mb < 4; ++mb)
#pragma unroll
    for (int kk = 0; kk < 2; ++kk) {
      bf16x8 kf = *(const bf16x8*)&Ks[mb * 16 + lr][kk * 32 + lq * 8];
      sa[mb] = __builtin_amdgcn_mfma_f32_16x16x32_bf16(kf, qf[kk], sa[mb], 0, 0, 0);
    }
  float sc[4][4];
  float m_new = m_i;
#pragma unroll
  for (int mb = 0; mb < 4; ++mb)
#pragma unroll
    for (int i = 0; i < 4; ++i) {
      float sv = sa[mb][i] * 0.125f;
      if (kt == qt_tile && (mb * 16 + lq4 + i) > qrow_l) sv = -3.0e4f;
      sc[mb][i] = sv;
      m_new = fmaxf(m_new, sv);
    }
  m_new = fmaxf(m_new, __shfl_xor(m_new, 16));
  m_new = fmaxf(m_new, __shfl_xor(m_new, 32));
  float alpha = __expf(m_i - m_new);
  m_i = m_new;
  float p[4][4], sm = 0.f;
#pragma unroll
  for (int mb = 0; mb < 4; ++mb)
#pragma unroll
    for (int i = 0; i < 4; ++i) { p[mb][i] = __expf(sc[mb][i] - m_new); sm += p[mb][i]; }
  sm += __shfl_xor(sm, 16);
  sm += __shfl_xor(sm, 32);
  l_i = l_i * alpha + sm;

  // P -> wave-private LDS rows, packed b64
#pragma unroll
  for (int mb = 0; mb < 4; ++mb) {
    uint2 pk;
    pk.x = (uint32_t)f2b(p[mb][0]) | ((uint32_t)f2b(p[mb][1]) << 16);
    pk.y = (uint32_t)f2b(p[mb][2]) | ((uint32_t)f2b(p[mb][3]) << 16);
    *(uint2*)&QP[w * 16 + lr][mb * 16 + lq4] = pk;
  }
#pragma unroll
  for (int i = 0; i < 4; ++i) {
    float ai = __shfl(alpha, base16 | (lq4 + i));
    o_acc[0][i] *= ai; o_acc[1][i] *= ai;
    o_acc[2][i] *= ai; o_acc[3][i] *= ai;
  }
  asm volatile("s_waitcnt lgkmcnt(0)" ::: "memory");
#pragma unroll
  for (int kk = 0; kk < 2; ++kk) {
    bf16x8 pf = *(const bf16x8*)&QP[w * 16 + lr][kk * 32 + lq * 8];
#pragma unroll
    for (int nb = 0; nb < 4; ++nb) {
      bf16x8 vf = *(const bf16x8*)&Vt[nb * 16 + lr][kk * 32 + lq * 8];
      o_acc[nb] = __builtin_amdgcn_mfma_f32_16x16x32_bf16(pf, vf, o_acc[nb], 0, 0, 0);
    }
  }
}

// ---------------------------------------------------------------------------
// Kernel 2: causal flash attention. THIS ROUND'S CHANGE: q-tile pairing
// (qtA = 31-bx, qtB = bx) -> uniform 33 tile-activations/block; K/V staged
// once per kt serves both tiles. Grid 16x32.
// ---------------------------------------------------------------------------
__global__ __launch_bounds__(256) void k_attn(const u16* __restrict__ Q,
                                              const u16* __restrict__ K,
                                              const u16* __restrict__ V,
                                              u16* __restrict__ AO) {
  __shared__ u16 QP[64][72];   // Q staging, then wave-private P scratch
  __shared__ u16 Ks[64][72];
  __shared__ u16 Vt[64][72];
  const int qtA = 31 - blockIdx.x;   // 16..31
  const int qtB = blockIdx.x;        // 0..15  (qtA > qtB always)
  const int bh = blockIdx.y;
  const int b = bh >> 4, h = bh & 15;
  const u16* Qg = Q + (bh * 2048) * 64;
  const u16* Kg = K + bh * 2048 * 64;
  const u16* Vg = V + (long)bh * 64 * 2048;
  const int t = threadIdx.x, w = t >> 6, lane = t & 63;
  const int lr = lane & 15, lq = lane >> 4;
  const int lq4 = lq * 4;
  const int base16 = lane & 48;
  const int r0 = t >> 3, c0 = (t & 7) * 8;
  const int qrow_l = w * 16 + lr;

  // stage Q tile A -> qfA, then Q tile B -> qfB (QP reused)
  bf16x8 qfA[2], qfB[2];
  *(uint4*)&QP[r0][c0]      = *(const uint4*)&Qg[(qtA * 64 + r0) * 64 + c0];
  *(uint4*)&QP[r0 + 32][c0] = *(const uint4*)&Qg[(qtA * 64 + r0 + 32) * 64 + c0];
  __syncthreads();
#pragma unroll
  for (int kk = 0; kk < 2; ++kk)
    qfA[kk] = *(const bf16x8*)&QP[w * 16 + lr][kk * 32 + lq * 8];
  __syncthreads();   // all qfA reads done before restage
  *(uint4*)&QP[r0][c0]      = *(const uint4*)&Qg[(qtB * 64 + r0) * 64 + c0];
  *(uint4*)&QP[r0 + 32][c0] = *(const uint4*)&Qg[(qtB * 64 + r0 + 32) * 64 + c0];
  __syncthreads();
#pragma unroll
  for (int kk = 0; kk < 2; ++kk)
    qfB[kk] = *(const bf16x8*)&QP[w * 16 + lr][kk * 32 + lq * 8];

  float m_iA = -3.0e4f, l_iA = 0.f, m_iB = -3.0e4f, l_iB = 0.f;
  f32x4 o_accA[4] = {}, o_accB[4] = {};

  for (int kt = 0; kt <= qtA; ++kt) {
    __syncthreads();   // prev tile's Ks/Vt (and P/qfB) reads done
    *(uint4*)&Ks[r0][c0]      = *(const uint4*)&Kg[(kt * 64 + r0) * 64 + c0];
    *(uint4*)&Ks[r0 + 32][c0] = *(const uint4*)&Kg[(kt * 64 + r0 + 32) * 64 + c0];
    *(uint4*)&Vt[r0][c0]      = *(const uint4*)&Vg[r0 * 2048 + kt * 64 + c0];
    *(uint4*)&Vt[r0 + 32][c0] = *(const uint4*)&Vg[(r0 + 32) * 2048 + kt * 64 + c0];
    __syncthreads();

    attn_tile(QP, Ks, Vt, qfA, o_accA, m_iA, l_iA, kt, qtA,
              w, lr, lq, lq4, base16, qrow_l);
    if (kt <= qtB) {
      // wave-private P rows: in-order DS pipe + fence orders A-reads vs B-writes
      asm volatile("s_waitcnt lgkmcnt(0)" ::: "memory");
      attn_tile(QP, Ks, Vt, qfB, o_accB, m_iB, l_iB, kt, qtB,
                w, lr, lq, lq4, base16, qrow_l);
    }
  }
  // epilogues
  float linvA = 1.0f / l_iA, linvB = 1.0f / l_iB;
#pragma unroll
  for (int i = 0; i < 4; ++i) {
    float invA = __shfl(linvA, base16 | (lq4 + i));
    float invB = __shfl(linvB, base16 | (lq4 + i));
    int rowA = qtA * 64 + w * 16 + lq4 + i;
    int rowB = qtB * 64 + w * 16 + lq4 + i;
    int obA = (b * 2048 + rowA) * 1024 + h * 64;
    int obB = (b * 2048 + rowB) * 1024 + h * 64;
#pragma unroll
    for (int nb = 0; nb < 4; ++nb) {
      AO[obA + nb * 16 + lr] = f2b(o_accA[nb][i] * invA);
      AO[obB + nb * 16 + lr] = f2b(o_accB[nb][i] * invB);
    }
  }
}

// ---------------------------------------------------------------------------
// Kernel 3: out = ao @ w_out^T. THIS ROUND: 2-n-tile fusion (R10 pattern) —
// stage A once, two B tiles, 8 MFMA/wave per barrier pair. Grid 8x64.
// ---------------------------------------------------------------------------
__global__ __launch_bounds__(256) void k_gemm_out(const u16* __restrict__ A,
                                                  const void* __restrict__ Bv,
                                                  const int* __restrict__ flag,
                                                  void* __restrict__ Cv) {
  __shared__ u16 As[64][40];
  __shared__ u16 Bs[2][64][40];
  const int mode = flag[0];
  const int n0 = blockIdx.x * 128, m0 = blockIdx.y * 64;
  const int t = threadIdx.x, w = t >> 6, lane = t & 63;
  const int lr = lane & 15, lq = lane >> 4;
  f32x4 acc[2][4] = {};
  const int rA = t >> 2, cA = (t & 3) * 8;
  const int aoff = (m0 + rA) * 1024 + cA;
  const int boff = (n0 + rA) * 1024 + cA;       // second tile: +64*1024
  for (int k0 = 0; k0 < 1024; k0 += 32) {
    __syncthreads();
    *(uint4*)&As[rA][cA] = *(const uint4*)(A + aoff + k0);
    if (mode == 0) {
      *(uint4*)&Bs[0][rA][cA] = *(const uint4*)((const u16*)Bv + boff + k0);
      *(uint4*)&Bs[1][rA][cA] = *(const uint4*)((const u16*)Bv + boff + 65536 + k0);
    } else {
      const float* Bf = (const float*)Bv;
#pragma unroll
      for (int e = 0; e < 8; ++e) {
        Bs[0][rA][cA + e] = f2b(Bf[boff + k0 + e]);
        Bs[1][rA][cA + e] = f2b(Bf[boff + 65536 + k0 + e]);
      }
    }
    __syncthreads();
    bf16x8 bfx[2];
#pragma unroll
    for (int e = 0; e < 2; ++e)
      bfx[e] = *(const bf16x8*)&Bs[e][(w << 4) + lr][lq * 8];
#pragma unroll
    for (int mt = 0; mt < 4; ++mt) {
      bf16x8 af = *(const bf16x8*)&As[(mt << 4) + lr][lq * 8];
#pragma unroll
      for (int e = 0; e < 2; ++e)
        acc[e][mt] = __builtin_amdgcn_mfma_f32_16x16x32_bf16(af, bfx[e], acc[e][mt], 0, 0, 0);
    }
  }
#pragma unroll
  for (int e = 0; e < 2; ++e) {
    const int col = n0 + e * 64 + (w << 4) + lr;
    if (mode == 0) {
      u16* C = (u16*)Cv;
#pragma unroll
      for (int mt = 0; mt < 4; ++mt)
#pragma unroll
        for (int i = 0; i < 4; ++i)
          C[(m0 + mt * 16 + lq * 4 + i) * 1024 + col] = f2b(acc[e][mt][i]);
    } else {
      float* C = (float*)Cv;
#pragma unroll
      for (int mt = 0; mt < 4; ++mt)
#pragma unroll
        for (int i = 0; i < 4; ++i)
          C[(m0 + mt * 16 + lq * 4 + i) * 1024 + col] = acc[e][mt][i];
    }
  }
}

// ---------------------------------------------------------------------------
extern "C" void kernel_launch(void* const* d_in, const int* in_sizes, int n_in,
                              void* d_out, int out_size, void* d_ws, size_t ws_size,
                              hipStream_t stream) {
  const void* x    = d_in[0];   // (4096,1024)
  const void* wqkv = d_in[1];   // (3072,1024)
  const void* wout = d_in[2];   // (1024,1024)

  // ws layout (R3/R8-verbatim): [flag 256B][q 8.39MB][k 8.39MB][v^T 8.39MB][ao]
  int* flag = (int*)d_ws;
  u16* qb = (u16*)((char*)d_ws + 256);
  u16* kb = qb + 4194304;
  u16* vb = kb + 4194304;
  u16* ao = vb + 4194304;

  k_detect  <<<dim3(1), 256, 0, stream>>>((const u16*)x, flag);
  k_qkv_rope<<<dim3(16, 64), 256, 0, stream>>>(x, wqkv, flag, qb, kb, vb);
  k_attn    <<<dim3(16, 32), 256, 0, stream>>>(qb, kb, vb, ao);
  k_gemm_out<<<dim3(8, 64), 256, 0, stream>>>(ao, wout, flag, d_out);
}

// Round 12
// 234.704 us; speedup vs baseline: 3.0731x; 1.0038x over previous
//
#include <hip/hip_runtime.h>
#include <stdint.h>

typedef uint16_t u16;
typedef __attribute__((ext_vector_type(8))) short bf16x8;
typedef __attribute__((ext_vector_type(4))) float f32x4;

__device__ inline u16 f2b(float f) {          // fp32 -> bf16 RNE
  uint32_t u = __float_as_uint(f);
  u += 0x7FFF + ((u >> 16) & 1);
  return (u16)(u >> 16);
}
__device__ inline float b2f(u16 h) {          // bf16 -> fp32 exact
  return __uint_as_float(((uint32_t)h) << 16);
}

// ---------------------------------------------------------------------------
// Dtype probe (R3-verbatim): mode 0 = bf16 inputs, 1 = fp32.
// ---------------------------------------------------------------------------
__global__ void k_detect(const u16* __restrict__ X, int* __restrict__ flag) {
  __shared__ int cnt;
  const int t = threadIdx.x;
  if (t == 0) cnt = 0;
  __syncthreads();
  float av = fabsf(b2f(X[t * 2]));
  int wild = (av < 1000.0f) ? 0 : 1;
  atomicAdd(&cnt, wild);
  __syncthreads();
  if (t == 0) flag[0] = (cnt > 16) ? 1 : 0;
}

// ---------------------------------------------------------------------------
// Kernel 1: qkv = x @ w_qkv^T. THIS ROUND: e-fused AND 2-m-tile fused —
// one block = (head, 2 m-tiles): stage 2 A + 3 B per K-step, 24 MFMA/wave
// per barrier pair. Epilogue = 6x R10-proven Cs round-trip. Grid 16x32.
// ---------------------------------------------------------------------------
__global__ __launch_bounds__(256) void k_qkv_rope(const void* __restrict__ Xv,
                                                  const void* __restrict__ Wv,
                                                  const int* __restrict__ flag,
                                                  u16* __restrict__ Qo,
                                                  u16* __restrict__ Ko,
                                                  u16* __restrict__ Vo) {
  __shared__ u16 As[2][64][40];
  __shared__ u16 Bs[3][64][40];
  __shared__ float Cs[64][66];
  const int mode = flag[0];
  const int h = blockIdx.x;               // head 0..15
  const int n0h = h * 64;
  const int m0 = blockIdx.y * 128;        // two 64-row m-tiles
  const int t = threadIdx.x, w = t >> 6, lane = t & 63;
  const int lr = lane & 15, lq = lane >> 4;
  f32x4 acc[3][2][4] = {};                // [e][m-half][mt]
  const int rA = t >> 2, cA = (t & 3) * 8;
  const int aoff0 = (m0 + rA) * 1024 + cA;
  const int aoff1 = (m0 + 64 + rA) * 1024 + cA;
  const int boff0 = (n0h + rA) * 1024 + cA;
  for (int k0 = 0; k0 < 1024; k0 += 32) {
    __syncthreads();
    if (mode == 0) {
      *(uint4*)&As[0][rA][cA] = *(const uint4*)((const u16*)Xv + aoff0 + k0);
      *(uint4*)&As[1][rA][cA] = *(const uint4*)((const u16*)Xv + aoff1 + k0);
      *(uint4*)&Bs[0][rA][cA] = *(const uint4*)((const u16*)Wv + boff0 + k0);
      *(uint4*)&Bs[1][rA][cA] = *(const uint4*)((const u16*)Wv + boff0 + 1048576 + k0);
      *(uint4*)&Bs[2][rA][cA] = *(const uint4*)((const u16*)Wv + boff0 + 2097152 + k0);
    } else {
      const float* Xf = (const float*)Xv;
      const float* Wf = (const float*)Wv;
#pragma unroll
      for (int ee = 0; ee < 8; ++ee) {
        As[0][rA][cA + ee] = f2b(Xf[aoff0 + k0 + ee]);
        As[1][rA][cA + ee] = f2b(Xf[aoff1 + k0 + ee]);
        Bs[0][rA][cA + ee] = f2b(Wf[boff0 + k0 + ee]);
        Bs[1][rA][cA + ee] = f2b(Wf[boff0 + 1048576 + k0 + ee]);
        Bs[2][rA][cA + ee] = f2b(Wf[boff0 + 2097152 + k0 + ee]);
      }
    }
    __syncthreads();
    bf16x8 bf[3];
#pragma unroll
    for (int e = 0; e < 3; ++e)
      bf[e] = *(const bf16x8*)&Bs[e][(w << 4) + lr][lq * 8];
#pragma unroll
    for (int mt = 0; mt < 4; ++mt) {
      bf16x8 af0 = *(const bf16x8*)&As[0][(mt << 4) + lr][lq * 8];
      bf16x8 af1 = *(const bf16x8*)&As[1][(mt << 4) + lr][lq * 8];
#pragma unroll
      for (int e = 0; e < 3; ++e) {
        acc[e][0][mt] = __builtin_amdgcn_mfma_f32_16x16x32_bf16(af0, bf[e], acc[e][0][mt], 0, 0, 0);
        acc[e][1][mt] = __builtin_amdgcn_mfma_f32_16x16x32_bf16(af1, bf[e], acc[e][1][mt], 0, 0, 0);
      }
    }
  }
  for (int f = 0; f < 2; ++f) {
    const int m0f = m0 + f * 64;
    for (int e = 0; e < 3; ++e) {
      __syncthreads();
      {
        const int col = (w << 4) + lr;
#pragma unroll
        for (int mt = 0; mt < 4; ++mt)
#pragma unroll
          for (int i = 0; i < 4; ++i)
            Cs[mt * 16 + lq * 4 + i][col] = acc[e][f][mt][i];
      }
      __syncthreads();
      if (e == 2) {
        const int sx = t & 63, dh0 = (t >> 6) * 16;
        const int m = m0f + sx, b = m >> 11, s = m & 2047;
        const long hb = (long)(b * 16 + h) * 64;
#pragma unroll
        for (int u = 0; u < 16; ++u) {
          int dh = dh0 + u;
          Vo[(hb + dh) * 2048 + s] = f2b(Cs[sx][dh]);
        }
      } else {
        const int r = t >> 2, dh0 = (t & 3) * 16;
        const int m = m0f + r, b = m >> 11, s = m & 2047;
        const int obase = ((b * 16 + h) * 2048 + s) * 64;
        u16* O = (e == 0) ? Qo : Ko;
#pragma unroll
        for (int u = 0; u < 16; ++u) {
          int dh = dh0 + u;
          float v  = Cs[r][dh];
          float vp = Cs[r][dh ^ 32];
          float sign = (dh < 32) ? -1.0f : 1.0f;
          float fr  = __expf((float)(dh & 31) * -0.28782314f);
          float ang = (float)s * fr;
          float sn = __sinf(ang), cs = __cosf(ang);
          O[obase + dh] = f2b(v * cs + sign * vp * sn);
        }
      }
    }
  }
}

// ---------------------------------------------------------------------------
// Per-tile attention body (R9-proven math, factored; per-tile qt/state).
// ---------------------------------------------------------------------------
__device__ __forceinline__ void attn_tile(u16 QP[64][72], u16 Ks[64][72],
                                          u16 Vt[64][72], const bf16x8 qf[2],
                                          f32x4 o_acc[4], float& m_i, float& l_i,
                                          int kt, int qt_tile, int w, int lr,
                                          int lq, int lq4, int base16, int qrow_l) {
  f32x4 sa[4] = {};
#pragma unroll
  for (int mb = 0; mb < 4; ++mb)
#pragma unroll
    for (int kk = 0; kk < 2; ++kk) {
      bf16x8 kf = *(const bf16x8*)&Ks[mb * 16 + lr][kk * 32 + lq * 8];
      sa[mb] = __builtin_amdgcn_mfma_f32_16x16x32_bf16(kf, qf[kk], sa[mb], 0, 0, 0);
    }
  float sc[4][4];
  float m_new = m_i;
#pragma unroll
  for (int mb = 0; mb < 4; ++mb)
#pragma unroll
    for (int i = 0; i < 4; ++i) {
      float sv = sa[mb][i] * 0.125f;
      if (kt == qt_tile && (mb * 16 + lq4 + i) > qrow_l) sv = -3.0e4f;
      sc[mb][i] = sv;
      m_new = fmaxf(m_new, sv);
    }
  m_new = fmaxf(m_new, __shfl_xor(m_new, 16));
  m_new = fmaxf(m_new, __shfl_xor(m_new, 32));
  float alpha = __expf(m_i - m_new);
  m_i = m_new;
  float p[4][4], sm = 0.f;
#pragma unroll
  for (int mb = 0; mb < 4; ++mb)
#pragma unroll
    for (int i = 0; i < 4; ++i) { p[mb][i] = __expf(sc[mb][i] - m_new); sm += p[mb][i]; }
  sm += __shfl_xor(sm, 16);
  sm += __shfl_xor(sm, 32);
  l_i = l_i * alpha + sm;
#pragma unroll
  for (int mb = 0; mb < 4; ++mb) {
    uint2 pk;
    pk.x = (uint32_t)f2b(p[mb][0]) | ((uint32_t)f2b(p[mb][1]) << 16);
    pk.y = (uint32_t)f2b(p[mb][2]) | ((uint32_t)f2b(p[mb][3]) << 16);
    *(uint2*)&QP[w * 16 + lr][mb * 16 + lq4] = pk;
  }
#pragma unroll
  for (int i = 0; i < 4; ++i) {
    float ai = __shfl(alpha, base16 | (lq4 + i));
    o_acc[0][i] *= ai; o_acc[1][i] *= ai;
    o_acc[2][i] *= ai; o_acc[3][i] *= ai;
  }
  asm volatile("s_waitcnt lgkmcnt(0)" ::: "memory");
#pragma unroll
  for (int kk = 0; kk < 2; ++kk) {
    bf16x8 pf = *(const bf16x8*)&QP[w * 16 + lr][kk * 32 + lq * 8];
#pragma unroll
    for (int nb = 0; nb < 4; ++nb) {
      bf16x8 vf = *(const bf16x8*)&Vt[nb * 16 + lr][kk * 32 + lq * 8];
      o_acc[nb] = __builtin_amdgcn_mfma_f32_16x16x32_bf16(pf, vf, o_acc[nb], 0, 0, 0);
    }
  }
}

// ---------------------------------------------------------------------------
// Kernel 2: causal flash attention, paired q-tiles (R11-verbatim).
// ---------------------------------------------------------------------------
__global__ __launch_bounds__(256) void k_attn(const u16* __restrict__ Q,
                                              const u16* __restrict__ K,
                                              const u16* __restrict__ V,
                                              u16* __restrict__ AO) {
  __shared__ u16 QP[64][72];
  __shared__ u16 Ks[64][72];
  __shared__ u16 Vt[64][72];
  const int qtA = 31 - blockIdx.x;
  const int qtB = blockIdx.x;
  const int bh = blockIdx.y;
  const int b = bh >> 4, h = bh & 15;
  const u16* Qg = Q + (bh * 2048) * 64;
  const u16* Kg = K + bh * 2048 * 64;
  const u16* Vg = V + (long)bh * 64 * 2048;
  const int t = threadIdx.x, w = t >> 6, lane = t & 63;
  const int lr = lane & 15, lq = lane >> 4;
  const int lq4 = lq * 4;
  const int base16 = lane & 48;
  const int r0 = t >> 3, c0 = (t & 7) * 8;
  const int qrow_l = w * 16 + lr;

  bf16x8 qfA[2], qfB[2];
  *(uint4*)&QP[r0][c0]      = *(const uint4*)&Qg[(qtA * 64 + r0) * 64 + c0];
  *(uint4*)&QP[r0 + 32][c0] = *(const uint4*)&Qg[(qtA * 64 + r0 + 32) * 64 + c0];
  __syncthreads();
#pragma unroll
  for (int kk = 0; kk < 2; ++kk)
    qfA[kk] = *(const bf16x8*)&QP[w * 16 + lr][kk * 32 + lq * 8];
  __syncthreads();
  *(uint4*)&QP[r0][c0]      = *(const uint4*)&Qg[(qtB * 64 + r0) * 64 + c0];
  *(uint4*)&QP[r0 + 32][c0] = *(const uint4*)&Qg[(qtB * 64 + r0 + 32) * 64 + c0];
  __syncthreads();
#pragma unroll
  for (int kk = 0; kk < 2; ++kk)
    qfB[kk] = *(const bf16x8*)&QP[w * 16 + lr][kk * 32 + lq * 8];

  float m_iA = -3.0e4f, l_iA = 0.f, m_iB = -3.0e4f, l_iB = 0.f;
  f32x4 o_accA[4] = {}, o_accB[4] = {};

  for (int kt = 0; kt <= qtA; ++kt) {
    __syncthreads();
    *(uint4*)&Ks[r0][c0]      = *(const uint4*)&Kg[(kt * 64 + r0) * 64 + c0];
    *(uint4*)&Ks[r0 + 32][c0] = *(const uint4*)&Kg[(kt * 64 + r0 + 32) * 64 + c0];
    *(uint4*)&Vt[r0][c0]      = *(const uint4*)&Vg[r0 * 2048 + kt * 64 + c0];
    *(uint4*)&Vt[r0 + 32][c0] = *(const uint4*)&Vg[(r0 + 32) * 2048 + kt * 64 + c0];
    __syncthreads();

    attn_tile(QP, Ks, Vt, qfA, o_accA, m_iA, l_iA, kt, qtA,
              w, lr, lq, lq4, base16, qrow_l);
    if (kt <= qtB) {
      asm volatile("s_waitcnt lgkmcnt(0)" ::: "memory");
      attn_tile(QP, Ks, Vt, qfB, o_accB, m_iB, l_iB, kt, qtB,
                w, lr, lq, lq4, base16, qrow_l);
    }
  }
  float linvA = 1.0f / l_iA, linvB = 1.0f / l_iB;
#pragma unroll
  for (int i = 0; i < 4; ++i) {
    float invA = __shfl(linvA, base16 | (lq4 + i));
    float invB = __shfl(linvB, base16 | (lq4 + i));
    int rowA = qtA * 64 + w * 16 + lq4 + i;
    int rowB = qtB * 64 + w * 16 + lq4 + i;
    int obA = (b * 2048 + rowA) * 1024 + h * 64;
    int obB = (b * 2048 + rowB) * 1024 + h * 64;
#pragma unroll
    for (int nb = 0; nb < 4; ++nb) {
      AO[obA + nb * 16 + lr] = f2b(o_accA[nb][i] * invA);
      AO[obB + nb * 16 + lr] = f2b(o_accB[nb][i] * invB);
    }
  }
}

// ---------------------------------------------------------------------------
// Kernel 3: out = ao @ w_out^T. THIS ROUND: 2-m x 2-n tile fusion —
// stage 2 A + 2 B per K-step, 16 MFMA/wave per barrier pair. Grid 8x32.
// ---------------------------------------------------------------------------
__global__ __launch_bounds__(256) void k_gemm_out(const u16* __restrict__ A,
                                                  const void* __restrict__ Bv,
                                                  const int* __restrict__ flag,
                                                  void* __restrict__ Cv) {
  __shared__ u16 As[2][64][40];
  __shared__ u16 Bs[2][64][40];
  const int mode = flag[0];
  const int n0 = blockIdx.x * 128, m0 = blockIdx.y * 128;
  const int t = threadIdx.x, w = t >> 6, lane = t & 63;
  const int lr = lane & 15, lq = lane >> 4;
  f32x4 acc[2][2][4] = {};                // [n-e][m-f][mt]
  const int rA = t >> 2, cA = (t & 3) * 8;
  const int aoff0 = (m0 + rA) * 1024 + cA;
  const int aoff1 = (m0 + 64 + rA) * 1024 + cA;
  const int boff = (n0 + rA) * 1024 + cA;
  for (int k0 = 0; k0 < 1024; k0 += 32) {
    __syncthreads();
    *(uint4*)&As[0][rA][cA] = *(const uint4*)(A + aoff0 + k0);
    *(uint4*)&As[1][rA][cA] = *(const uint4*)(A + aoff1 + k0);
    if (mode == 0) {
      *(uint4*)&Bs[0][rA][cA] = *(const uint4*)((const u16*)Bv + boff + k0);
      *(uint4*)&Bs[1][rA][cA] = *(const uint4*)((const u16*)Bv + boff + 65536 + k0);
    } else {
      const float* Bf = (const float*)Bv;
#pragma unroll
      for (int e = 0; e < 8; ++e) {
        Bs[0][rA][cA + e] = f2b(Bf[boff + k0 + e]);
        Bs[1][rA][cA + e] = f2b(Bf[boff + 65536 + k0 + e]);
      }
    }
    __syncthreads();
    bf16x8 bfx[2];
#pragma unroll
    for (int e = 0; e < 2; ++e)
      bfx[e] = *(const bf16x8*)&Bs[e][(w << 4) + lr][lq * 8];
#pragma unroll
    for (int mt = 0; mt < 4; ++mt) {
      bf16x8 af0 = *(const bf16x8*)&As[0][(mt << 4) + lr][lq * 8];
      bf16x8 af1 = *(const bf16x8*)&As[1][(mt << 4) + lr][lq * 8];
#pragma unroll
      for (int e = 0; e < 2; ++e) {
        acc[e][0][mt] = __builtin_amdgcn_mfma_f32_16x16x32_bf16(af0, bfx[e], acc[e][0][mt], 0, 0, 0);
        acc[e][1][mt] = __builtin_amdgcn_mfma_f32_16x16x32_bf16(af1, bfx[e], acc[e][1][mt], 0, 0, 0);
      }
    }
  }
#pragma unroll
  for (int e = 0; e < 2; ++e)
#pragma unroll
    for (int f = 0; f < 2; ++f) {
      const int col = n0 + e * 64 + (w << 4) + lr;
      const int m0f = m0 + f * 64;
      if (mode == 0) {
        u16* C = (u16*)Cv;
#pragma unroll
        for (int mt = 0; mt < 4; ++mt)
#pragma unroll
          for (int i = 0; i < 4; ++i)
            C[(m0f + mt * 16 + lq * 4 + i) * 1024 + col] = f2b(acc[e][f][mt][i]);
      } else {
        float* C = (float*)Cv;
#pragma unroll
        for (int mt = 0; mt < 4; ++mt)
#pragma unroll
          for (int i = 0; i < 4; ++i)
            C[(m0f + mt * 16 + lq * 4 + i) * 1024 + col] = acc[e][f][mt][i];
      }
    }
}

// ---------------------------------------------------------------------------
extern "C" void kernel_launch(void* const* d_in, const int* in_sizes, int n_in,
                              void* d_out, int out_size, void* d_ws, size_t ws_size,
                              hipStream_t stream) {
  const void* x    = d_in[0];   // (4096,1024)
  const void* wqkv = d_in[1];   // (3072,1024)
  const void* wout = d_in[2];   // (1024,1024)

  // ws layout (R3/R8-verbatim): [flag 256B][q 8.39MB][k 8.39MB][v^T 8.39MB][ao]
  int* flag = (int*)d_ws;
  u16* qb = (u16*)((char*)d_ws + 256);
  u16* kb = qb + 4194304;
  u16* vb = kb + 4194304;
  u16* ao = vb + 4194304;

  k_detect  <<<dim3(1), 256, 0, stream>>>((const u16*)x, flag);
  k_qkv_rope<<<dim3(16, 32), 256, 0, stream>>>(x, wqkv, flag, qb, kb, vb);
  k_attn    <<<dim3(16, 32), 256, 0, stream>>>(qb, kb, vb, ao);
  k_gemm_out<<<dim3(8, 32), 256, 0, stream>>>(ao, wout, flag, d_out);
}

// Round 13
// 229.469 us; speedup vs baseline: 3.1432x; 1.0228x over previous
//
#include <hip/hip_runtime.h>
#include <stdint.h>

typedef uint16_t u16;
typedef __attribute__((ext_vector_type(8))) short bf16x8;
typedef __attribute__((ext_vector_type(4))) float f32x4;

__device__ inline u16 f2b(float f) {          // fp32 -> bf16 RNE
  uint32_t u = __float_as_uint(f);
  u += 0x7FFF + ((u >> 16) & 1);
  return (u16)(u >> 16);
}
__device__ inline float b2f(u16 h) {          // bf16 -> fp32 exact
  return __uint_as_float(((uint32_t)h) << 16);
}

// ---------------------------------------------------------------------------
// Dtype probe (R3-verbatim): mode 0 = bf16 inputs, 1 = fp32.
// ---------------------------------------------------------------------------
__global__ void k_detect(const u16* __restrict__ X, int* __restrict__ flag) {
  __shared__ int cnt;
  const int t = threadIdx.x;
  if (t == 0) cnt = 0;
  __syncthreads();
  float av = fabsf(b2f(X[t * 2]));
  int wild = (av < 1000.0f) ? 0 : 1;
  atomicAdd(&cnt, wild);
  __syncthreads();
  if (t == 0) flag[0] = (cnt > 16) ? 1 : 0;
}

// ---------------------------------------------------------------------------
// Kernel 1: qkv = x @ w_qkv^T, e-fused + 2-m-tile fused (R12 structure).
// THIS ROUND: register-prefetch software pipelining of the staging loads —
// iter k+1's global loads issue before iter k's MFMA, hiding HBM/L2 latency
// behind the compute instead of exposing it on the barrier chain.
// ---------------------------------------------------------------------------
__global__ __launch_bounds__(256) void k_qkv_rope(const void* __restrict__ Xv,
                                                  const void* __restrict__ Wv,
                                                  const int* __restrict__ flag,
                                                  u16* __restrict__ Qo,
                                                  u16* __restrict__ Ko,
                                                  u16* __restrict__ Vo) {
  __shared__ u16 As[2][64][40];
  __shared__ u16 Bs[3][64][40];
  __shared__ float Cs[64][66];
  const int mode = flag[0];
  const int h = blockIdx.x;               // head 0..15
  const int n0h = h * 64;
  const int m0 = blockIdx.y * 128;        // two 64-row m-tiles
  const int t = threadIdx.x, w = t >> 6, lane = t & 63;
  const int lr = lane & 15, lq = lane >> 4;
  f32x4 acc[3][2][4] = {};                // [e][m-half][mt]
  const int rA = t >> 2, cA = (t & 3) * 8;
  const int aoff0 = (m0 + rA) * 1024 + cA;
  const int aoff1 = (m0 + 64 + rA) * 1024 + cA;
  const int boff0 = (n0h + rA) * 1024 + cA;

  if (mode == 0) {
    const u16* Xp = (const u16*)Xv;
    const u16* Wp = (const u16*)Wv;
    uint4 pa0 = *(const uint4*)(Xp + aoff0);
    uint4 pa1 = *(const uint4*)(Xp + aoff1);
    uint4 pb0 = *(const uint4*)(Wp + boff0);
    uint4 pb1 = *(const uint4*)(Wp + boff0 + 1048576);
    uint4 pb2 = *(const uint4*)(Wp + boff0 + 2097152);
    for (int k0 = 0; k0 < 1024; k0 += 32) {
      __syncthreads();                    // prior frag reads done
      *(uint4*)&As[0][rA][cA] = pa0;
      *(uint4*)&As[1][rA][cA] = pa1;
      *(uint4*)&Bs[0][rA][cA] = pb0;
      *(uint4*)&Bs[1][rA][cA] = pb1;
      *(uint4*)&Bs[2][rA][cA] = pb2;
      __syncthreads();                    // writes visible
      if (k0 + 32 < 1024) {               // prefetch k+1 (overlaps MFMA below)
        const int kn = k0 + 32;
        pa0 = *(const uint4*)(Xp + aoff0 + kn);
        pa1 = *(const uint4*)(Xp + aoff1 + kn);
        pb0 = *(const uint4*)(Wp + boff0 + kn);
        pb1 = *(const uint4*)(Wp + boff0 + 1048576 + kn);
        pb2 = *(const uint4*)(Wp + boff0 + 2097152 + kn);
      }
      bf16x8 bf[3];
#pragma unroll
      for (int e = 0; e < 3; ++e)
        bf[e] = *(const bf16x8*)&Bs[e][(w << 4) + lr][lq * 8];
#pragma unroll
      for (int mt = 0; mt < 4; ++mt) {
        bf16x8 af0 = *(const bf16x8*)&As[0][(mt << 4) + lr][lq * 8];
        bf16x8 af1 = *(const bf16x8*)&As[1][(mt << 4) + lr][lq * 8];
#pragma unroll
        for (int e = 0; e < 3; ++e) {
          acc[e][0][mt] = __builtin_amdgcn_mfma_f32_16x16x32_bf16(af0, bf[e], acc[e][0][mt], 0, 0, 0);
          acc[e][1][mt] = __builtin_amdgcn_mfma_f32_16x16x32_bf16(af1, bf[e], acc[e][1][mt], 0, 0, 0);
        }
      }
    }
  } else {
    // fp32 fallback (dead in practice): R12-verbatim unpipelined loop
    for (int k0 = 0; k0 < 1024; k0 += 32) {
      __syncthreads();
      const float* Xf = (const float*)Xv;
      const float* Wf = (const float*)Wv;
#pragma unroll
      for (int ee = 0; ee < 8; ++ee) {
        As[0][rA][cA + ee] = f2b(Xf[aoff0 + k0 + ee]);
        As[1][rA][cA + ee] = f2b(Xf[aoff1 + k0 + ee]);
        Bs[0][rA][cA + ee] = f2b(Wf[boff0 + k0 + ee]);
        Bs[1][rA][cA + ee] = f2b(Wf[boff0 + 1048576 + k0 + ee]);
        Bs[2][rA][cA + ee] = f2b(Wf[boff0 + 2097152 + k0 + ee]);
      }
      __syncthreads();
      bf16x8 bf[3];
#pragma unroll
      for (int e = 0; e < 3; ++e)
        bf[e] = *(const bf16x8*)&Bs[e][(w << 4) + lr][lq * 8];
#pragma unroll
      for (int mt = 0; mt < 4; ++mt) {
        bf16x8 af0 = *(const bf16x8*)&As[0][(mt << 4) + lr][lq * 8];
        bf16x8 af1 = *(const bf16x8*)&As[1][(mt << 4) + lr][lq * 8];
#pragma unroll
        for (int e = 0; e < 3; ++e) {
          acc[e][0][mt] = __builtin_amdgcn_mfma_f32_16x16x32_bf16(af0, bf[e], acc[e][0][mt], 0, 0, 0);
          acc[e][1][mt] = __builtin_amdgcn_mfma_f32_16x16x32_bf16(af1, bf[e], acc[e][1][mt], 0, 0, 0);
        }
      }
    }
  }

  // epilogue: 6x Cs round-trip (R12-verbatim)
  for (int f = 0; f < 2; ++f) {
    const int m0f = m0 + f * 64;
    for (int e = 0; e < 3; ++e) {
      __syncthreads();
      {
        const int col = (w << 4) + lr;
#pragma unroll
        for (int mt = 0; mt < 4; ++mt)
#pragma unroll
          for (int i = 0; i < 4; ++i)
            Cs[mt * 16 + lq * 4 + i][col] = acc[e][f][mt][i];
      }
      __syncthreads();
      if (e == 2) {
        const int sx = t & 63, dh0 = (t >> 6) * 16;
        const int m = m0f + sx, b = m >> 11, s = m & 2047;
        const long hb = (long)(b * 16 + h) * 64;
#pragma unroll
        for (int u = 0; u < 16; ++u) {
          int dh = dh0 + u;
          Vo[(hb + dh) * 2048 + s] = f2b(Cs[sx][dh]);
        }
      } else {
        const int r = t >> 2, dh0 = (t & 3) * 16;
        const int m = m0f + r, b = m >> 11, s = m & 2047;
        const int obase = ((b * 16 + h) * 2048 + s) * 64;
        u16* O = (e == 0) ? Qo : Ko;
#pragma unroll
        for (int u = 0; u < 16; ++u) {
          int dh = dh0 + u;
          float v  = Cs[r][dh];
          float vp = Cs[r][dh ^ 32];
          float sign = (dh < 32) ? -1.0f : 1.0f;
          float fr  = __expf((float)(dh & 31) * -0.28782314f);
          float ang = (float)s * fr;
          float sn = __sinf(ang), cs = __cosf(ang);
          O[obase + dh] = f2b(v * cs + sign * vp * sn);
        }
      }
    }
  }
}

// ---------------------------------------------------------------------------
// Per-tile attention body (R9-proven math, factored; per-tile qt/state).
// ---------------------------------------------------------------------------
__device__ __forceinline__ void attn_tile(u16 QP[64][72], u16 Ks[64][72],
                                          u16 Vt[64][72], const bf16x8 qf[2],
                                          f32x4 o_acc[4], float& m_i, float& l_i,
                                          int kt, int qt_tile, int w, int lr,
                                          int lq, int lq4, int base16, int qrow_l) {
  f32x4 sa[4] = {};
#pragma unroll
  for (int mb = 0; mb < 4; ++mb)
#pragma unroll
    for (int kk = 0; kk < 2; ++kk) {
      bf16x8 kf = *(const bf16x8*)&Ks[mb * 16 + lr][kk * 32 + lq * 8];
      sa[mb] = __builtin_amdgcn_mfma_f32_16x16x32_bf16(kf, qf[kk], sa[mb], 0, 0, 0);
    }
  float sc[4][4];
  float m_new = m_i;
#pragma unroll
  for (int mb = 0; mb < 4; ++mb)
#pragma unroll
    for (int i = 0; i < 4; ++i) {
      float sv = sa[mb][i] * 0.125f;
      if (kt == qt_tile && (mb * 16 + lq4 + i) > qrow_l) sv = -3.0e4f;
      sc[mb][i] = sv;
      m_new = fmaxf(m_new, sv);
    }
  m_new = fmaxf(m_new, __shfl_xor(m_new, 16));
  m_new = fmaxf(m_new, __shfl_xor(m_new, 32));
  float alpha = __expf(m_i - m_new);
  m_i = m_new;
  float p[4][4], sm = 0.f;
#pragma unroll
  for (int mb = 0; mb < 4; ++mb)
#pragma unroll
    for (int i = 0; i < 4; ++i) { p[mb][i] = __expf(sc[mb][i] - m_new); sm += p[mb][i]; }
  sm += __shfl_xor(sm, 16);
  sm += __shfl_xor(sm, 32);
  l_i = l_i * alpha + sm;
#pragma unroll
  for (int mb = 0; mb < 4; ++mb) {
    uint2 pk;
    pk.x = (uint32_t)f2b(p[mb][0]) | ((uint32_t)f2b(p[mb][1]) << 16);
    pk.y = (uint32_t)f2b(p[mb][2]) | ((uint32_t)f2b(p[mb][3]) << 16);
    *(uint2*)&QP[w * 16 + lr][mb * 16 + lq4] = pk;
  }
#pragma unroll
  for (int i = 0; i < 4; ++i) {
    float ai = __shfl(alpha, base16 | (lq4 + i));
    o_acc[0][i] *= ai; o_acc[1][i] *= ai;
    o_acc[2][i] *= ai; o_acc[3][i] *= ai;
  }
  asm volatile("s_waitcnt lgkmcnt(0)" ::: "memory");
#pragma unroll
  for (int kk = 0; kk < 2; ++kk) {
    bf16x8 pf = *(const bf16x8*)&QP[w * 16 + lr][kk * 32 + lq * 8];
#pragma unroll
    for (int nb = 0; nb < 4; ++nb) {
      bf16x8 vf = *(const bf16x8*)&Vt[nb * 16 + lr][kk * 32 + lq * 8];
      o_acc[nb] = __builtin_amdgcn_mfma_f32_16x16x32_bf16(pf, vf, o_acc[nb], 0, 0, 0);
    }
  }
}

// ---------------------------------------------------------------------------
// Kernel 2: causal flash attention, paired q-tiles (R11-verbatim).
// ---------------------------------------------------------------------------
__global__ __launch_bounds__(256) void k_attn(const u16* __restrict__ Q,
                                              const u16* __restrict__ K,
                                              const u16* __restrict__ V,
                                              u16* __restrict__ AO) {
  __shared__ u16 QP[64][72];
  __shared__ u16 Ks[64][72];
  __shared__ u16 Vt[64][72];
  const int qtA = 31 - blockIdx.x;
  const int qtB = blockIdx.x;
  const int bh = blockIdx.y;
  const int b = bh >> 4, h = bh & 15;
  const u16* Qg = Q + (bh * 2048) * 64;
  const u16* Kg = K + bh * 2048 * 64;
  const u16* Vg = V + (long)bh * 64 * 2048;
  const int t = threadIdx.x, w = t >> 6, lane = t & 63;
  const int lr = lane & 15, lq = lane >> 4;
  const int lq4 = lq * 4;
  const int base16 = lane & 48;
  const int r0 = t >> 3, c0 = (t & 7) * 8;
  const int qrow_l = w * 16 + lr;

  bf16x8 qfA[2], qfB[2];
  *(uint4*)&QP[r0][c0]      = *(const uint4*)&Qg[(qtA * 64 + r0) * 64 + c0];
  *(uint4*)&QP[r0 + 32][c0] = *(const uint4*)&Qg[(qtA * 64 + r0 + 32) * 64 + c0];
  __syncthreads();
#pragma unroll
  for (int kk = 0; kk < 2; ++kk)
    qfA[kk] = *(const bf16x8*)&QP[w * 16 + lr][kk * 32 + lq * 8];
  __syncthreads();
  *(uint4*)&QP[r0][c0]      = *(const uint4*)&Qg[(qtB * 64 + r0) * 64 + c0];
  *(uint4*)&QP[r0 + 32][c0] = *(const uint4*)&Qg[(qtB * 64 + r0 + 32) * 64 + c0];
  __syncthreads();
#pragma unroll
  for (int kk = 0; kk < 2; ++kk)
    qfB[kk] = *(const bf16x8*)&QP[w * 16 + lr][kk * 32 + lq * 8];

  float m_iA = -3.0e4f, l_iA = 0.f, m_iB = -3.0e4f, l_iB = 0.f;
  f32x4 o_accA[4] = {}, o_accB[4] = {};

  for (int kt = 0; kt <= qtA; ++kt) {
    __syncthreads();
    *(uint4*)&Ks[r0][c0]      = *(const uint4*)&Kg[(kt * 64 + r0) * 64 + c0];
    *(uint4*)&Ks[r0 + 32][c0] = *(const uint4*)&Kg[(kt * 64 + r0 + 32) * 64 + c0];
    *(uint4*)&Vt[r0][c0]      = *(const uint4*)&Vg[r0 * 2048 + kt * 64 + c0];
    *(uint4*)&Vt[r0 + 32][c0] = *(const uint4*)&Vg[(r0 + 32) * 2048 + kt * 64 + c0];
    __syncthreads();

    attn_tile(QP, Ks, Vt, qfA, o_accA, m_iA, l_iA, kt, qtA,
              w, lr, lq, lq4, base16, qrow_l);
    if (kt <= qtB) {
      asm volatile("s_waitcnt lgkmcnt(0)" ::: "memory");
      attn_tile(QP, Ks, Vt, qfB, o_accB, m_iB, l_iB, kt, qtB,
                w, lr, lq, lq4, base16, qrow_l);
    }
  }
  float linvA = 1.0f / l_iA, linvB = 1.0f / l_iB;
#pragma unroll
  for (int i = 0; i < 4; ++i) {
    float invA = __shfl(linvA, base16 | (lq4 + i));
    float invB = __shfl(linvB, base16 | (lq4 + i));
    int rowA = qtA * 64 + w * 16 + lq4 + i;
    int rowB = qtB * 64 + w * 16 + lq4 + i;
    int obA = (b * 2048 + rowA) * 1024 + h * 64;
    int obB = (b * 2048 + rowB) * 1024 + h * 64;
#pragma unroll
    for (int nb = 0; nb < 4; ++nb) {
      AO[obA + nb * 16 + lr] = f2b(o_accA[nb][i] * invA);
      AO[obB + nb * 16 + lr] = f2b(o_accB[nb][i] * invB);
    }
  }
}

// ---------------------------------------------------------------------------
// Kernel 3: out = ao @ w_out^T, 2-m x 2-n fused. THIS ROUND: same register-
// prefetch pipelining as k_qkv_rope.
// ---------------------------------------------------------------------------
__global__ __launch_bounds__(256) void k_gemm_out(const u16* __restrict__ A,
                                                  const void* __restrict__ Bv,
                                                  const int* __restrict__ flag,
                                                  void* __restrict__ Cv) {
  __shared__ u16 As[2][64][40];
  __shared__ u16 Bs[2][64][40];
  const int mode = flag[0];
  const int n0 = blockIdx.x * 128, m0 = blockIdx.y * 128;
  const int t = threadIdx.x, w = t >> 6, lane = t & 63;
  const int lr = lane & 15, lq = lane >> 4;
  f32x4 acc[2][2][4] = {};                // [n-e][m-f][mt]
  const int rA = t >> 2, cA = (t & 3) * 8;
  const int aoff0 = (m0 + rA) * 1024 + cA;
  const int aoff1 = (m0 + 64 + rA) * 1024 + cA;
  const int boff = (n0 + rA) * 1024 + cA;

  if (mode == 0) {
    const u16* Bp = (const u16*)Bv;
    uint4 pa0 = *(const uint4*)(A + aoff0);
    uint4 pa1 = *(const uint4*)(A + aoff1);
    uint4 pb0 = *(const uint4*)(Bp + boff);
    uint4 pb1 = *(const uint4*)(Bp + boff + 65536);
    for (int k0 = 0; k0 < 1024; k0 += 32) {
      __syncthreads();
      *(uint4*)&As[0][rA][cA] = pa0;
      *(uint4*)&As[1][rA][cA] = pa1;
      *(uint4*)&Bs[0][rA][cA] = pb0;
      *(uint4*)&Bs[1][rA][cA] = pb1;
      __syncthreads();
      if (k0 + 32 < 1024) {
        const int kn = k0 + 32;
        pa0 = *(const uint4*)(A + aoff0 + kn);
        pa1 = *(const uint4*)(A + aoff1 + kn);
        pb0 = *(const uint4*)(Bp + boff + kn);
        pb1 = *(const uint4*)(Bp + boff + 65536 + kn);
      }
      bf16x8 bfx[2];
#pragma unroll
      for (int e = 0; e < 2; ++e)
        bfx[e] = *(const bf16x8*)&Bs[e][(w << 4) + lr][lq * 8];
#pragma unroll
      for (int mt = 0; mt < 4; ++mt) {
        bf16x8 af0 = *(const bf16x8*)&As[0][(mt << 4) + lr][lq * 8];
        bf16x8 af1 = *(const bf16x8*)&As[1][(mt << 4) + lr][lq * 8];
#pragma unroll
        for (int e = 0; e < 2; ++e) {
          acc[e][0][mt] = __builtin_amdgcn_mfma_f32_16x16x32_bf16(af0, bfx[e], acc[e][0][mt], 0, 0, 0);
          acc[e][1][mt] = __builtin_amdgcn_mfma_f32_16x16x32_bf16(af1, bfx[e], acc[e][1][mt], 0, 0, 0);
        }
      }
    }
  } else {
    // fp32 fallback (dead in practice): R12-verbatim
    for (int k0 = 0; k0 < 1024; k0 += 32) {
      __syncthreads();
      *(uint4*)&As[0][rA][cA] = *(const uint4*)(A + aoff0 + k0);
      *(uint4*)&As[1][rA][cA] = *(const uint4*)(A + aoff1 + k0);
      const float* Bf = (const float*)Bv;
#pragma unroll
      for (int e = 0; e < 8; ++e) {
        Bs[0][rA][cA + e] = f2b(Bf[boff + k0 + e]);
        Bs[1][rA][cA + e] = f2b(Bf[boff + 65536 + k0 + e]);
      }
      __syncthreads();
      bf16x8 bfx[2];
#pragma unroll
      for (int e = 0; e < 2; ++e)
        bfx[e] = *(const bf16x8*)&Bs[e][(w << 4) + lr][lq * 8];
#pragma unroll
      for (int mt = 0; mt < 4; ++mt) {
        bf16x8 af0 = *(const bf16x8*)&As[0][(mt << 4) + lr][lq * 8];
        bf16x8 af1 = *(const bf16x8*)&As[1][(mt << 4) + lr][lq * 8];
#pragma unroll
        for (int e = 0; e < 2; ++e) {
          acc[e][0][mt] = __builtin_amdgcn_mfma_f32_16x16x32_bf16(af0, bfx[e], acc[e][0][mt], 0, 0, 0);
          acc[e][1][mt] = __builtin_amdgcn_mfma_f32_16x16x32_bf16(af1, bfx[e], acc[e][1][mt], 0, 0, 0);
        }
      }
    }
  }
#pragma unroll
  for (int e = 0; e < 2; ++e)
#pragma unroll
    for (int f = 0; f < 2; ++f) {
      const int col = n0 + e * 64 + (w << 4) + lr;
      const int m0f = m0 + f * 64;
      if (mode == 0) {
        u16* C = (u16*)Cv;
#pragma unroll
        for (int mt = 0; mt < 4; ++mt)
#pragma unroll
          for (int i = 0; i < 4; ++i)
            C[(m0f + mt * 16 + lq * 4 + i) * 1024 + col] = f2b(acc[e][f][mt][i]);
      } else {
        float* C = (float*)Cv;
#pragma unroll
        for (int mt = 0; mt < 4; ++mt)
#pragma unroll
          for (int i = 0; i < 4; ++i)
            C[(m0f + mt * 16 + lq * 4 + i) * 1024 + col] = acc[e][f][mt][i];
      }
    }
}

// ---------------------------------------------------------------------------
extern "C" void kernel_launch(void* const* d_in, const int* in_sizes, int n_in,
                              void* d_out, int out_size, void* d_ws, size_t ws_size,
                              hipStream_t stream) {
  const void* x    = d_in[0];   // (4096,1024)
  const void* wqkv = d_in[1];   // (3072,1024)
  const void* wout = d_in[2];   // (1024,1024)

  // ws layout (R3/R8-verbatim): [flag 256B][q 8.39MB][k 8.39MB][v^T 8.39MB][ao]
  int* flag = (int*)d_ws;
  u16* qb = (u16*)((char*)d_ws + 256);
  u16* kb = qb + 4194304;
  u16* vb = kb + 4194304;
  u16* ao = vb + 4194304;

  k_detect  <<<dim3(1), 256, 0, stream>>>((const u16*)x, flag);
  k_qkv_rope<<<dim3(16, 32), 256, 0, stream>>>(x, wqkv, flag, qb, kb, vb);
  k_attn    <<<dim3(16, 32), 256, 0, stream>>>(qb, kb, vb, ao);
  k_gemm_out<<<dim3(8, 32), 256, 0, stream>>>(ao, wout, flag, d_out);
}